// Round 1
// baseline (1953.298 us; speedup 1.0000x reference)
//
#include <hip/hip_runtime.h>
#include <math.h>

#define BATCH 8
#define NPTS 4096
#define SSAMP 256
#define KNBR 128
#define GGRID 2025

__device__ __forceinline__ float lrelu01(float v) { return v > 0.f ? v : 0.01f * v; }

// ---------------------------------------------------------------- 1) x = lrelu(pos @ Wt + bt)
__global__ void xform_kernel(const float* __restrict__ pos, const float* __restrict__ Wt,
                             const float* __restrict__ bt, float* __restrict__ x) {
    int o = blockIdx.x * 256 + threadIdx.x;          // B*N*64 = 2,097,152 exact
    int c = o & 63, p = o >> 6;
    const float* pr = pos + (size_t)p * 3;
    float v = fmaf(pr[2], Wt[128 + c], fmaf(pr[1], Wt[64 + c], fmaf(pr[0], Wt[c], bt[c])));
    x[o] = lrelu01(v);
}

// ---------------------------------------------------------------- 2) FPS (one block per cloud)
__global__ void __launch_bounds__(512) fps_kernel(const float* __restrict__ pos,
                                                  int* __restrict__ fpsidx,
                                                  float* __restrict__ newpos) {
    int b = blockIdx.x, t = threadIdx.x;
    const float* P = pos + (size_t)b * NPTS * 3;
    float px[8], py[8], pz[8], mind[8];
#pragma unroll
    for (int j = 0; j < 8; ++j) {
        int n = t + 512 * j;
        px[j] = P[n * 3 + 0]; py[j] = P[n * 3 + 1]; pz[j] = P[n * 3 + 2];
        mind[j] = 3.402823466e+38f;
    }
    __shared__ float cpt[3];
    __shared__ unsigned long long red[8];
    if (t == 0) {
        fpsidx[b * SSAMP] = 0;
        newpos[(size_t)b * SSAMP * 3 + 0] = P[0];
        newpos[(size_t)b * SSAMP * 3 + 1] = P[1];
        newpos[(size_t)b * SSAMP * 3 + 2] = P[2];
        cpt[0] = P[0]; cpt[1] = P[1]; cpt[2] = P[2];
    }
    __syncthreads();
    for (int s = 1; s < SSAMP; ++s) {
        float cx = cpt[0], cy = cpt[1], cz = cpt[2];
        unsigned long long best = 0ull;
#pragma unroll
        for (int j = 0; j < 8; ++j) {
            float dx = __fsub_rn(px[j], cx), dy = __fsub_rn(py[j], cy), dz = __fsub_rn(pz[j], cz);
            float d = __fadd_rn(__fadd_rn(__fmul_rn(dx, dx), __fmul_rn(dy, dy)), __fmul_rn(dz, dz));
            mind[j] = fminf(mind[j], d);
            unsigned long long key = ((unsigned long long)__float_as_uint(mind[j]) << 32)
                                   | (unsigned int)(~(unsigned int)(t + 512 * j));
            if (key > best) best = key;
        }
#pragma unroll
        for (int off = 32; off > 0; off >>= 1) {
            unsigned long long o = __shfl_down(best, off, 64);
            if (o > best) best = o;
        }
        if ((t & 63) == 0) red[t >> 6] = best;
        __syncthreads();
        if (t < 64) {
            unsigned long long bb = (t < 8) ? red[t] : 0ull;
#pragma unroll
            for (int off = 4; off > 0; off >>= 1) {
                unsigned long long o = __shfl_down(bb, off, 64);
                if (o > bb) bb = o;
            }
            if (t == 0) {
                int nx = (int)(~(unsigned int)(bb & 0xFFFFFFFFull));
                fpsidx[b * SSAMP + s] = nx;
                float X = P[(size_t)nx * 3], Y = P[(size_t)nx * 3 + 1], Z = P[(size_t)nx * 3 + 2];
                newpos[((size_t)b * SSAMP + s) * 3 + 0] = X;
                newpos[((size_t)b * SSAMP + s) * 3 + 1] = Y;
                newpos[((size_t)b * SSAMP + s) * 3 + 2] = Z;
                cpt[0] = X; cpt[1] = Y; cpt[2] = Z;
            }
        }
        __syncthreads();
    }
}

// ---------------------------------------------------------------- 3) radius ball query (one wave per (b,s))
__global__ void __launch_bounds__(256) ballq_kernel(const float* __restrict__ pos,
                                                    const float* __restrict__ newpos,
                                                    int* __restrict__ nidx) {
    int w = blockIdx.x * 4 + (threadIdx.x >> 6);     // 0..2047 = b*256+s
    int lane = threadIdx.x & 63;
    int b = w >> 8;
    const float* P = pos + (size_t)b * NPTS * 3;
    float qx = newpos[w * 3 + 0], qy = newpos[w * 3 + 1], qz = newpos[w * 3 + 2];
    int* out = nidx + (size_t)w * KNBR;
    int base = 0;
    for (int c = 0; c < 64; ++c) {
        int n = c * 64 + lane;
        float dx = __fsub_rn(P[n * 3 + 0], qx);
        float dy = __fsub_rn(P[n * 3 + 1], qy);
        float dz = __fsub_rn(P[n * 3 + 2], qz);
        float d2 = __fadd_rn(__fadd_rn(__fmul_rn(dx, dx), __fmul_rn(dy, dy)), __fmul_rn(dz, dz));
        bool in = (d2 <= 0.04f);
        unsigned long long mask = __ballot(in);
        if (in) {
            int p = base + __popcll(mask & ((1ull << lane) - 1ull));
            if (p < KNBR) out[p] = n;
        }
        base += __popcll(mask);
        if (base >= KNBR) break;
    }
    for (int p = base + lane; p < KNBR; p += 64) out[p] = -1;
}

// ---------------------------------------------------------------- 4) fused PointConv + max-agg (one block per (b,s))
__global__ void __launch_bounds__(256, 3) pointconv_kernel(
    const float* __restrict__ x, const float* __restrict__ pos,
    const float* __restrict__ newpos, const int* __restrict__ nidx,
    const float* __restrict__ Wc1, const float* __restrict__ bc1,
    const float* __restrict__ Wc2, const float* __restrict__ bc2,
    const float* __restrict__ Wc3, const float* __restrict__ bc3,
    float* __restrict__ agg) {
    __shared__ float feat[32][68];
    __shared__ float h1s[32][64];
    __shared__ float h2s[32][132];
    __shared__ int vld[128];
    __shared__ float mred[4][512];
    int bs = blockIdx.x;
    int b = bs >> 8;
    int t = threadIdx.x;
    const float* npp = newpos + (size_t)bs * 3;
    float qx = npp[0], qy = npp[1], qz = npp[2];
    if (t < 128) vld[t] = nidx[(size_t)bs * KNBR + t];
    __syncthreads();
    int cog = t & 63, kq = t >> 6;
    int co0 = cog * 8;
    float4 b3a = *(const float4*)(bc3 + co0);
    float4 b3b = *(const float4*)(bc3 + co0 + 4);
    float m[8];
#pragma unroll
    for (int c = 0; c < 8; ++c) m[c] = -3.402823466e+38f;

    for (int kc = 0; kc < 4; ++kc) {
        int kbase = kc * 32;
        // stage feat rows [kbase, kbase+32)
        for (int e = t; e < 32 * 67; e += 256) {
            int kk = e / 67, c = e - kk * 67;
            int n = vld[kbase + kk];
            float v = 0.f;
            if (n >= 0) {
                if (c < 64) v = x[((size_t)b * NPTS + n) * 64 + c];
                else {
                    int d = c - 64;
                    float pv = pos[((size_t)b * NPTS + n) * 3 + d];
                    float qv = (d == 0) ? qx : (d == 1) ? qy : qz;
                    v = __fsub_rn(pv, qv);
                }
            }
            feat[kk][c] = v;
        }
        __syncthreads();
        // layer 1: 32x64
        for (int o = t; o < 32 * 64; o += 256) {
            int kk = o >> 6, c1 = o & 63;
            float acc = bc1[c1];
            const float4* fr = (const float4*)feat[kk];
#pragma unroll
            for (int ci4 = 0; ci4 < 16; ++ci4) {
                float4 fv = fr[ci4];
                acc = fmaf(fv.x, Wc1[(ci4 * 4 + 0) * 64 + c1], acc);
                acc = fmaf(fv.y, Wc1[(ci4 * 4 + 1) * 64 + c1], acc);
                acc = fmaf(fv.z, Wc1[(ci4 * 4 + 2) * 64 + c1], acc);
                acc = fmaf(fv.w, Wc1[(ci4 * 4 + 3) * 64 + c1], acc);
            }
            acc = fmaf(feat[kk][64], Wc1[64 * 64 + c1], acc);
            acc = fmaf(feat[kk][65], Wc1[65 * 64 + c1], acc);
            acc = fmaf(feat[kk][66], Wc1[66 * 64 + c1], acc);
            h1s[kk][c1] = lrelu01(acc);
        }
        __syncthreads();
        // layer 2: 32x128
        for (int o = t; o < 32 * 128; o += 256) {
            int kk = o >> 7, c2 = o & 127;
            float acc = bc2[c2];
            const float4* hr = (const float4*)h1s[kk];
#pragma unroll
            for (int ci4 = 0; ci4 < 16; ++ci4) {
                float4 hv = hr[ci4];
                acc = fmaf(hv.x, Wc2[(ci4 * 4 + 0) * 128 + c2], acc);
                acc = fmaf(hv.y, Wc2[(ci4 * 4 + 1) * 128 + c2], acc);
                acc = fmaf(hv.z, Wc2[(ci4 * 4 + 2) * 128 + c2], acc);
                acc = fmaf(hv.w, Wc2[(ci4 * 4 + 3) * 128 + c2], acc);
            }
            h2s[kk][c2] = lrelu01(acc);
        }
        __syncthreads();
        // layer 3 partial (+lrelu+masked max): rows kq*8..kq*8+7, cols co0..co0+7
        float acc[8][8];
#pragma unroll
        for (int j = 0; j < 8; ++j) {
            acc[j][0] = b3a.x; acc[j][1] = b3a.y; acc[j][2] = b3a.z; acc[j][3] = b3a.w;
            acc[j][4] = b3b.x; acc[j][5] = b3b.y; acc[j][6] = b3b.z; acc[j][7] = b3b.w;
        }
        for (int ci = 0; ci < 128; ci += 4) {
            float4 hv[8];
#pragma unroll
            for (int j = 0; j < 8; ++j) hv[j] = *(const float4*)&h2s[kq * 8 + j][ci];
#pragma unroll
            for (int cc = 0; cc < 4; ++cc) {
                float4 wA = *(const float4*)(Wc3 + (size_t)(ci + cc) * 512 + co0);
                float4 wB = *(const float4*)(Wc3 + (size_t)(ci + cc) * 512 + co0 + 4);
#pragma unroll
                for (int j = 0; j < 8; ++j) {
                    float h = (cc == 0) ? hv[j].x : (cc == 1) ? hv[j].y : (cc == 2) ? hv[j].z : hv[j].w;
                    acc[j][0] = fmaf(h, wA.x, acc[j][0]);
                    acc[j][1] = fmaf(h, wA.y, acc[j][1]);
                    acc[j][2] = fmaf(h, wA.z, acc[j][2]);
                    acc[j][3] = fmaf(h, wA.w, acc[j][3]);
                    acc[j][4] = fmaf(h, wB.x, acc[j][4]);
                    acc[j][5] = fmaf(h, wB.y, acc[j][5]);
                    acc[j][6] = fmaf(h, wB.z, acc[j][6]);
                    acc[j][7] = fmaf(h, wB.w, acc[j][7]);
                }
            }
        }
#pragma unroll
        for (int j = 0; j < 8; ++j) {
            if (vld[kbase + kq * 8 + j] >= 0) {
#pragma unroll
                for (int c = 0; c < 8; ++c) m[c] = fmaxf(m[c], lrelu01(acc[j][c]));
            }
        }
        __syncthreads();
    }
#pragma unroll
    for (int c = 0; c < 8; ++c) mred[kq][co0 + c] = m[c];
    __syncthreads();
    if (t < 64) {
#pragma unroll
        for (int c = 0; c < 8; ++c) {
            float v = fmaxf(fmaxf(mred[0][t * 8 + c], mred[1][t * 8 + c]),
                            fmaxf(mred[2][t * 8 + c], mred[3][t * 8 + c]));
            agg[(size_t)bs * 512 + t * 8 + c] = v;
        }
    }
}

// ---------------------------------------------------------------- 5) encin = cat[agg, newpos]
__global__ void encin_kernel(const float* __restrict__ agg, const float* __restrict__ newpos,
                             float* __restrict__ encin) {
    int o = blockIdx.x * 256 + threadIdx.x;
    if (o >= 2048 * 515) return;
    int r = o / 515, c = o - r * 515;
    encin[o] = (c < 512) ? agg[r * 512 + c] : newpos[r * 3 + (c - 512)];
}

// ---------------------------------------------------------------- generic GEMM: C = act(A@W + b), 8 rows x 512 cols per block
__global__ void __launch_bounds__(256) gemm_rb8(const float* __restrict__ A,
                                                const float* __restrict__ W,
                                                const float* __restrict__ bias,
                                                float* __restrict__ C,
                                                int Kdim, int cols, int act) {
    extern __shared__ float a[];
    int lda = (Kdim + 3) & ~3;
    int t = threadIdx.x;
    int row0 = blockIdx.x * 8;
    for (int r = 0; r < 8; ++r)
        for (int c = t; c < Kdim; c += 256)
            a[r * lda + c] = A[(size_t)(row0 + r) * Kdim + c];
    __syncthreads();
    int co = blockIdx.y * 512 + t * 2;
    float2 bv = *(const float2*)(bias + co);
    float acc[8][2];
#pragma unroll
    for (int r = 0; r < 8; ++r) { acc[r][0] = bv.x; acc[r][1] = bv.y; }
    int ci = 0;
    for (; ci + 4 <= Kdim; ci += 4) {
        float4 av[8];
#pragma unroll
        for (int r = 0; r < 8; ++r) av[r] = *(const float4*)&a[r * lda + ci];
        const float* Wp = W + (size_t)ci * cols + co;
        float2 w0 = *(const float2*)(Wp);
        float2 w1 = *(const float2*)(Wp + (size_t)cols);
        float2 w2 = *(const float2*)(Wp + 2 * (size_t)cols);
        float2 w3 = *(const float2*)(Wp + 3 * (size_t)cols);
#pragma unroll
        for (int r = 0; r < 8; ++r) {
            acc[r][0] = fmaf(av[r].x, w0.x, acc[r][0]); acc[r][1] = fmaf(av[r].x, w0.y, acc[r][1]);
            acc[r][0] = fmaf(av[r].y, w1.x, acc[r][0]); acc[r][1] = fmaf(av[r].y, w1.y, acc[r][1]);
            acc[r][0] = fmaf(av[r].z, w2.x, acc[r][0]); acc[r][1] = fmaf(av[r].z, w2.y, acc[r][1]);
            acc[r][0] = fmaf(av[r].w, w3.x, acc[r][0]); acc[r][1] = fmaf(av[r].w, w3.y, acc[r][1]);
        }
    }
    for (; ci < Kdim; ++ci) {
        float w0 = W[(size_t)ci * cols + co], w1 = W[(size_t)ci * cols + co + 1];
#pragma unroll
        for (int r = 0; r < 8; ++r) {
            float av = a[r * lda + ci];
            acc[r][0] = fmaf(av, w0, acc[r][0]);
            acc[r][1] = fmaf(av, w1, acc[r][1]);
        }
    }
#pragma unroll
    for (int r = 0; r < 8; ++r) {
        float v0 = acc[r][0], v1 = acc[r][1];
        if (act == 1) { v0 = fmaxf(v0, 0.f); v1 = fmaxf(v1, 0.f); }
        else if (act == 2) { v0 = lrelu01(v0); v1 = lrelu01(v1); }
        *(float2*)&C[(size_t)(row0 + r) * cols + co] = make_float2(v0, v1);
    }
}

// ---------------------------------------------------------------- 8) vote aggregation
__global__ void votes_kernel(const float* __restrict__ e, float* __restrict__ z) {
    int o = blockIdx.x * 256 + threadIdx.x;          // 8192 exact
    int b = o >> 10, c = o & 1023;
    const float* eb = e + (size_t)b * SSAMP * 2048;
    float num = 0.f, den = 0.f;
    for (int s = 0; s < SSAMP; ++s) {
        float mean = eb[(size_t)s * 2048 + c];
        float lv = eb[(size_t)s * 2048 + 1024 + c];
        float sd = expf(0.5f * lv);
        num += mean / sd;
        den += 1.f / sd;
    }
    z[o] = num / den;
}

// ---------------------------------------------------------------- 9) u = z @ Wf[0:1024] + b (both decoders)
__global__ void ukern(const float* __restrict__ z, const float* __restrict__ Wf11,
                      const float* __restrict__ bf11, const float* __restrict__ Wf21,
                      const float* __restrict__ bf21, float* __restrict__ u1,
                      float* __restrict__ u2) {
    const float* W = blockIdx.y ? Wf21 : Wf11;
    const float* bs_ = blockIdx.y ? bf21 : bf11;
    float* out = blockIdx.y ? u2 : u1;
    int co = blockIdx.x * 64 + (threadIdx.x & 63);
    int r0 = (threadIdx.x >> 6) * 2;
    float acc0 = bs_[co], acc1 = bs_[co];
    for (int ci = 0; ci < 1024; ++ci) {
        float w = W[(size_t)ci * 512 + co];
        acc0 = fmaf(z[r0 * 1024 + ci], w, acc0);
        acc1 = fmaf(z[(r0 + 1) * 1024 + ci], w, acc1);
    }
    out[r0 * 512 + co] = acc0;
    out[(r0 + 1) * 512 + co] = acc1;
}

// ---------------------------------------------------------------- 10) fold1 first layer: relu(u1 + gx*Wrow1024 + gy*Wrow1025)
__global__ void fold1_kernel(const float* __restrict__ u1, const float* __restrict__ Wf11,
                             float* __restrict__ f1) {
    int o = blockIdx.x * 256 + threadIdx.x;          // 8*2025*512 exact
    int co = o & 511;
    int rg = o >> 9;
    int b = rg / 2025;
    int g = rg - b * 2025;
    int i = g / 45, j = g - i * 45;
    float gx = (j == 44) ? 0.3f : (float)(-0.3 + j * (0.6 / 44.0));
    float gy = (i == 44) ? 0.3f : (float)(-0.3 + i * (0.6 / 44.0));
    float v = u1[(b << 9) + co];
    v = fmaf(gx, Wf11[1024 * 512 + co], v);
    v = fmaf(gy, Wf11[1025 * 512 + co], v);
    f1[o] = fmaxf(v, 0.f);
}

// ---------------------------------------------------------------- 13) fold2 first layer: relu(u2 + sum_j p_j*Wrow(1024+j))
__global__ void fold2_kernel(const float* __restrict__ u2, const float* __restrict__ Wf21,
                             const float* __restrict__ pts, float* __restrict__ f2) {
    int o = blockIdx.x * 256 + threadIdx.x;
    int co = o & 511;
    int rg = o >> 9;
    int b = rg / 2025;
    float p0 = pts[rg * 3 + 0], p1 = pts[rg * 3 + 1], p2 = pts[rg * 3 + 2];
    float v = u2[(b << 9) + co];
    v = fmaf(p0, Wf21[1024 * 512 + co], v);
    v = fmaf(p1, Wf21[1025 * 512 + co], v);
    v = fmaf(p2, Wf21[1026 * 512 + co], v);
    f2[o] = fmaxf(v, 0.f);
}

// ---------------------------------------------------------------- final 512->3 projections
__global__ void smallout_kernel(const float* __restrict__ H, const float* __restrict__ Wf,
                                const float* __restrict__ bf, float* __restrict__ out, int total) {
    int o = blockIdx.x * 256 + threadIdx.x;
    if (o >= total) return;
    int rg = o / 3, c = o - rg * 3;
    const float* h = H + (size_t)rg * 512;
    float a0 = 0.f, a1 = 0.f, a2 = 0.f, a3 = 0.f;
    for (int ci = 0; ci < 512; ci += 4) {
        a0 = fmaf(h[ci + 0], Wf[(ci + 0) * 3 + c], a0);
        a1 = fmaf(h[ci + 1], Wf[(ci + 1) * 3 + c], a1);
        a2 = fmaf(h[ci + 2], Wf[(ci + 2) * 3 + c], a2);
        a3 = fmaf(h[ci + 3], Wf[(ci + 3) * 3 + c], a3);
    }
    out[o] = a0 + a1 + a2 + a3 + bf[c];
}

extern "C" void kernel_launch(void* const* d_in, const int* in_sizes, int n_in,
                              void* d_out, int out_size, void* d_ws, size_t ws_size,
                              hipStream_t stream) {
    const float* pos  = (const float*)d_in[0];
    const float* Wt   = (const float*)d_in[1];
    const float* bt   = (const float*)d_in[2];
    const float* Wc1  = (const float*)d_in[3];
    const float* bc1  = (const float*)d_in[4];
    const float* Wc2  = (const float*)d_in[5];
    const float* bc2  = (const float*)d_in[6];
    const float* Wc3  = (const float*)d_in[7];
    const float* bc3  = (const float*)d_in[8];
    const float* We1  = (const float*)d_in[9];
    const float* be1  = (const float*)d_in[10];
    const float* We2  = (const float*)d_in[11];
    const float* be2  = (const float*)d_in[12];
    const float* Wf11 = (const float*)d_in[13];
    const float* bf11 = (const float*)d_in[14];
    const float* Wf12 = (const float*)d_in[15];
    const float* bf12 = (const float*)d_in[16];
    const float* Wf13 = (const float*)d_in[17];
    const float* bf13 = (const float*)d_in[18];
    const float* Wf21 = (const float*)d_in[19];
    const float* bf21 = (const float*)d_in[20];
    const float* Wf22 = (const float*)d_in[21];
    const float* bf22 = (const float*)d_in[22];
    const float* Wf23 = (const float*)d_in[23];
    const float* bf23 = (const float*)d_in[24];
    float* out = (float*)d_out;

    float* wsf = (float*)d_ws;
    // seg1 lives until votes; f1 (decoder activations) aliases it afterwards.
    size_t off = 0;
    float* x     = wsf + off; off += 2097152;   // [B,N,64]
    float* aggb  = wsf + off; off += 1048576;   // [B,S,512]
    float* encin = wsf + off; off += 1054720;   // [2048,515]
    float* e1    = wsf + off; off += 1048576;   // [2048,512]
    float* e     = wsf + off; off += 4194304;   // [2048,2048]  seg1 end = 9,443,328 floats
    float* f1    = wsf;                         // alias of seg1: [16200,512] = 8,294,400 floats
    off = 9443328;
    float* h12   = wsf + off; off += 8294400;   // [16200,512]
    float* zb    = wsf + off; off += 8192;      // [8,1024]
    float* u1    = wsf + off; off += 4096;
    float* u2    = wsf + off; off += 4096;
    float* pts   = wsf + off; off += 48600;     // fold1 output [16200,3]
    float* newp  = wsf + off; off += 6144;      // [B,S,3]
    int*   fpsix = (int*)(wsf + off); off += 2048;
    int*   nix   = (int*)(wsf + off); off += 262144;

    xform_kernel<<<8192, 256, 0, stream>>>(pos, Wt, bt, x);
    fps_kernel<<<BATCH, 512, 0, stream>>>(pos, fpsix, newp);
    ballq_kernel<<<512, 256, 0, stream>>>(pos, newp, nix);
    pointconv_kernel<<<2048, 256, 0, stream>>>(x, pos, newp, nix, Wc1, bc1, Wc2, bc2, Wc3, bc3, aggb);
    encin_kernel<<<4120, 256, 0, stream>>>(aggb, newp, encin);
    gemm_rb8<<<dim3(256, 1), 256, 516 * 8 * 4, stream>>>(encin, We1, be1, e1, 515, 512, 2);
    gemm_rb8<<<dim3(256, 4), 256, 512 * 8 * 4, stream>>>(e1, We2, be2, e, 512, 2048, 0);
    votes_kernel<<<32, 256, 0, stream>>>(e, zb);
    ukern<<<dim3(8, 2), 256, 0, stream>>>(zb, Wf11, bf11, Wf21, bf21, u1, u2);
    fold1_kernel<<<32400, 256, 0, stream>>>(u1, Wf11, f1);
    gemm_rb8<<<dim3(2025, 1), 256, 512 * 8 * 4, stream>>>(f1, Wf12, bf12, h12, 512, 512, 1);
    smallout_kernel<<<190, 256, 0, stream>>>(h12, Wf13, bf13, pts, 48600);
    fold2_kernel<<<32400, 256, 0, stream>>>(u2, Wf21, pts, f1);
    gemm_rb8<<<dim3(2025, 1), 256, 512 * 8 * 4, stream>>>(f1, Wf22, bf22, h12, 512, 512, 1);
    smallout_kernel<<<190, 256, 0, stream>>>(h12, Wf23, bf23, out, 48600);
}

// Round 2
// 1693.305 us; speedup vs baseline: 1.1535x; 1.1535x over previous
//
#include <hip/hip_runtime.h>
#include <math.h>

#define BATCH 8
#define NPTS 4096
#define SSAMP 256
#define KNBR 128
#define GGRID 2025

__device__ __forceinline__ float lrelu01(float v) { return v > 0.f ? v : 0.01f * v; }

// ---------------------------------------------------------------- 1) x = lrelu(pos @ Wt + bt)
__global__ void xform_kernel(const float* __restrict__ pos, const float* __restrict__ Wt,
                             const float* __restrict__ bt, float* __restrict__ x) {
    int o = blockIdx.x * 256 + threadIdx.x;          // B*N*64 = 2,097,152 exact
    int c = o & 63, p = o >> 6;
    const float* pr = pos + (size_t)p * 3;
    float v = fmaf(pr[2], Wt[128 + c], fmaf(pr[1], Wt[64 + c], fmaf(pr[0], Wt[c], bt[c])));
    x[o] = lrelu01(v);
}

// ---------------------------------------------------------------- 2) FPS (one block per cloud)
__global__ void __launch_bounds__(512) fps_kernel(const float* __restrict__ pos,
                                                  int* __restrict__ fpsidx,
                                                  float* __restrict__ newpos) {
    int b = blockIdx.x, t = threadIdx.x;
    const float* P = pos + (size_t)b * NPTS * 3;
    float px[8], py[8], pz[8], mind[8];
#pragma unroll
    for (int j = 0; j < 8; ++j) {
        int n = t + 512 * j;
        px[j] = P[n * 3 + 0]; py[j] = P[n * 3 + 1]; pz[j] = P[n * 3 + 2];
        mind[j] = 3.402823466e+38f;
    }
    __shared__ float cpt[3];
    __shared__ unsigned long long red[8];
    if (t == 0) {
        fpsidx[b * SSAMP] = 0;
        newpos[(size_t)b * SSAMP * 3 + 0] = P[0];
        newpos[(size_t)b * SSAMP * 3 + 1] = P[1];
        newpos[(size_t)b * SSAMP * 3 + 2] = P[2];
        cpt[0] = P[0]; cpt[1] = P[1]; cpt[2] = P[2];
    }
    __syncthreads();
    for (int s = 1; s < SSAMP; ++s) {
        float cx = cpt[0], cy = cpt[1], cz = cpt[2];
        unsigned long long best = 0ull;
#pragma unroll
        for (int j = 0; j < 8; ++j) {
            float dx = __fsub_rn(px[j], cx), dy = __fsub_rn(py[j], cy), dz = __fsub_rn(pz[j], cz);
            float d = __fadd_rn(__fadd_rn(__fmul_rn(dx, dx), __fmul_rn(dy, dy)), __fmul_rn(dz, dz));
            mind[j] = fminf(mind[j], d);
            unsigned long long key = ((unsigned long long)__float_as_uint(mind[j]) << 32)
                                   | (unsigned int)(~(unsigned int)(t + 512 * j));
            if (key > best) best = key;
        }
#pragma unroll
        for (int off = 32; off > 0; off >>= 1) {
            unsigned long long o = __shfl_down(best, off, 64);
            if (o > best) best = o;
        }
        if ((t & 63) == 0) red[t >> 6] = best;
        __syncthreads();
        if (t < 64) {
            unsigned long long bb = (t < 8) ? red[t] : 0ull;
#pragma unroll
            for (int off = 4; off > 0; off >>= 1) {
                unsigned long long o = __shfl_down(bb, off, 64);
                if (o > bb) bb = o;
            }
            if (t == 0) {
                int nx = (int)(~(unsigned int)(bb & 0xFFFFFFFFull));
                fpsidx[b * SSAMP + s] = nx;
                float X = P[(size_t)nx * 3], Y = P[(size_t)nx * 3 + 1], Z = P[(size_t)nx * 3 + 2];
                newpos[((size_t)b * SSAMP + s) * 3 + 0] = X;
                newpos[((size_t)b * SSAMP + s) * 3 + 1] = Y;
                newpos[((size_t)b * SSAMP + s) * 3 + 2] = Z;
                cpt[0] = X; cpt[1] = Y; cpt[2] = Z;
            }
        }
        __syncthreads();
    }
}

// ---------------------------------------------------------------- 3) radius ball query (one wave per (b,s))
__global__ void __launch_bounds__(256) ballq_kernel(const float* __restrict__ pos,
                                                    const float* __restrict__ newpos,
                                                    int* __restrict__ nidx) {
    int w = blockIdx.x * 4 + (threadIdx.x >> 6);     // 0..2047 = b*256+s
    int lane = threadIdx.x & 63;
    int b = w >> 8;
    const float* P = pos + (size_t)b * NPTS * 3;
    float qx = newpos[w * 3 + 0], qy = newpos[w * 3 + 1], qz = newpos[w * 3 + 2];
    int* out = nidx + (size_t)w * KNBR;
    int base = 0;
    for (int c = 0; c < 64; ++c) {
        int n = c * 64 + lane;
        float dx = __fsub_rn(P[n * 3 + 0], qx);
        float dy = __fsub_rn(P[n * 3 + 1], qy);
        float dz = __fsub_rn(P[n * 3 + 2], qz);
        float d2 = __fadd_rn(__fadd_rn(__fmul_rn(dx, dx), __fmul_rn(dy, dy)), __fmul_rn(dz, dz));
        bool in = (d2 <= 0.04f);
        unsigned long long mask = __ballot(in);
        if (in) {
            int p = base + __popcll(mask & ((1ull << lane) - 1ull));
            if (p < KNBR) out[p] = n;
        }
        base += __popcll(mask);
        if (base >= KNBR) break;
    }
    for (int p = base + lane; p < KNBR; p += 64) out[p] = -1;
}

// ---------------------------------------------------------------- 4) fused PointConv + max-agg (one block per (b,s))
// __launch_bounds__(256, 2): VGPR cap 256 so the 8x8 fp32 accumulator tile
// stays in registers. (256,3) capped allocation -> acc spilled to scratch:
// R1 counters showed 525 MB WRITE_SIZE for a 4 MB output.
__global__ void __launch_bounds__(256, 2) pointconv_kernel(
    const float* __restrict__ x, const float* __restrict__ pos,
    const float* __restrict__ newpos, const int* __restrict__ nidx,
    const float* __restrict__ Wc1, const float* __restrict__ bc1,
    const float* __restrict__ Wc2, const float* __restrict__ bc2,
    const float* __restrict__ Wc3, const float* __restrict__ bc3,
    float* __restrict__ agg) {
    __shared__ float feat[32][68];
    __shared__ float h1s[32][64];
    __shared__ float h2s[32][132];
    __shared__ int vld[128];
    __shared__ float mred[4][512];
    int bs = blockIdx.x;
    int b = bs >> 8;
    int t = threadIdx.x;
    const float* npp = newpos + (size_t)bs * 3;
    float qx = npp[0], qy = npp[1], qz = npp[2];
    if (t < 128) vld[t] = nidx[(size_t)bs * KNBR + t];
    __syncthreads();
    int cog = t & 63, kq = t >> 6;
    int co0 = cog * 8;
    float4 b3a = *(const float4*)(bc3 + co0);
    float4 b3b = *(const float4*)(bc3 + co0 + 4);
    float m[8];
#pragma unroll
    for (int c = 0; c < 8; ++c) m[c] = -3.402823466e+38f;

    for (int kc = 0; kc < 4; ++kc) {
        int kbase = kc * 32;
        // stage feat rows [kbase, kbase+32)
        for (int e = t; e < 32 * 67; e += 256) {
            int kk = e / 67, c = e - kk * 67;
            int n = vld[kbase + kk];
            float v = 0.f;
            if (n >= 0) {
                if (c < 64) v = x[((size_t)b * NPTS + n) * 64 + c];
                else {
                    int d = c - 64;
                    float pv = pos[((size_t)b * NPTS + n) * 3 + d];
                    float qv = (d == 0) ? qx : (d == 1) ? qy : qz;
                    v = __fsub_rn(pv, qv);
                }
            }
            feat[kk][c] = v;
        }
        __syncthreads();
        // layer 1: 32x64
        for (int o = t; o < 32 * 64; o += 256) {
            int kk = o >> 6, c1 = o & 63;
            float acc = bc1[c1];
            const float4* fr = (const float4*)feat[kk];
#pragma unroll
            for (int ci4 = 0; ci4 < 16; ++ci4) {
                float4 fv = fr[ci4];
                acc = fmaf(fv.x, Wc1[(ci4 * 4 + 0) * 64 + c1], acc);
                acc = fmaf(fv.y, Wc1[(ci4 * 4 + 1) * 64 + c1], acc);
                acc = fmaf(fv.z, Wc1[(ci4 * 4 + 2) * 64 + c1], acc);
                acc = fmaf(fv.w, Wc1[(ci4 * 4 + 3) * 64 + c1], acc);
            }
            acc = fmaf(feat[kk][64], Wc1[64 * 64 + c1], acc);
            acc = fmaf(feat[kk][65], Wc1[65 * 64 + c1], acc);
            acc = fmaf(feat[kk][66], Wc1[66 * 64 + c1], acc);
            h1s[kk][c1] = lrelu01(acc);
        }
        __syncthreads();
        // layer 2: 32x128
        for (int o = t; o < 32 * 128; o += 256) {
            int kk = o >> 7, c2 = o & 127;
            float acc = bc2[c2];
            const float4* hr = (const float4*)h1s[kk];
#pragma unroll
            for (int ci4 = 0; ci4 < 16; ++ci4) {
                float4 hv = hr[ci4];
                acc = fmaf(hv.x, Wc2[(ci4 * 4 + 0) * 128 + c2], acc);
                acc = fmaf(hv.y, Wc2[(ci4 * 4 + 1) * 128 + c2], acc);
                acc = fmaf(hv.z, Wc2[(ci4 * 4 + 2) * 128 + c2], acc);
                acc = fmaf(hv.w, Wc2[(ci4 * 4 + 3) * 128 + c2], acc);
            }
            h2s[kk][c2] = lrelu01(acc);
        }
        __syncthreads();
        // layer 3 partial (+lrelu+masked max): rows kq*8..kq*8+7, cols co0..co0+7
        float acc[8][8];
#pragma unroll
        for (int j = 0; j < 8; ++j) {
            acc[j][0] = b3a.x; acc[j][1] = b3a.y; acc[j][2] = b3a.z; acc[j][3] = b3a.w;
            acc[j][4] = b3b.x; acc[j][5] = b3b.y; acc[j][6] = b3b.z; acc[j][7] = b3b.w;
        }
        for (int ci = 0; ci < 128; ci += 4) {
            float4 hv[8];
#pragma unroll
            for (int j = 0; j < 8; ++j) hv[j] = *(const float4*)&h2s[kq * 8 + j][ci];
#pragma unroll
            for (int cc = 0; cc < 4; ++cc) {
                float4 wA = *(const float4*)(Wc3 + (size_t)(ci + cc) * 512 + co0);
                float4 wB = *(const float4*)(Wc3 + (size_t)(ci + cc) * 512 + co0 + 4);
#pragma unroll
                for (int j = 0; j < 8; ++j) {
                    float h = (cc == 0) ? hv[j].x : (cc == 1) ? hv[j].y : (cc == 2) ? hv[j].z : hv[j].w;
                    acc[j][0] = fmaf(h, wA.x, acc[j][0]);
                    acc[j][1] = fmaf(h, wA.y, acc[j][1]);
                    acc[j][2] = fmaf(h, wA.z, acc[j][2]);
                    acc[j][3] = fmaf(h, wA.w, acc[j][3]);
                    acc[j][4] = fmaf(h, wB.x, acc[j][4]);
                    acc[j][5] = fmaf(h, wB.y, acc[j][5]);
                    acc[j][6] = fmaf(h, wB.z, acc[j][6]);
                    acc[j][7] = fmaf(h, wB.w, acc[j][7]);
                }
            }
        }
#pragma unroll
        for (int j = 0; j < 8; ++j) {
            if (vld[kbase + kq * 8 + j] >= 0) {
#pragma unroll
                for (int c = 0; c < 8; ++c) m[c] = fmaxf(m[c], lrelu01(acc[j][c]));
            }
        }
        __syncthreads();
    }
#pragma unroll
    for (int c = 0; c < 8; ++c) mred[kq][co0 + c] = m[c];
    __syncthreads();
    if (t < 64) {
#pragma unroll
        for (int c = 0; c < 8; ++c) {
            float v = fmaxf(fmaxf(mred[0][t * 8 + c], mred[1][t * 8 + c]),
                            fmaxf(mred[2][t * 8 + c], mred[3][t * 8 + c]));
            agg[(size_t)bs * 512 + t * 8 + c] = v;
        }
    }
}

// ---------------------------------------------------------------- 5) encin = cat[agg, newpos]
__global__ void encin_kernel(const float* __restrict__ agg, const float* __restrict__ newpos,
                             float* __restrict__ encin) {
    int o = blockIdx.x * 256 + threadIdx.x;
    if (o >= 2048 * 515) return;
    int r = o / 515, c = o - r * 515;
    encin[o] = (c < 512) ? agg[r * 512 + c] : newpos[r * 3 + (c - 512)];
}

// ---------------------------------------------------------------- generic GEMM: C = act(A@W + b), 8 rows x 512 cols per block
__global__ void __launch_bounds__(256) gemm_rb8(const float* __restrict__ A,
                                                const float* __restrict__ W,
                                                const float* __restrict__ bias,
                                                float* __restrict__ C,
                                                int Kdim, int cols, int act) {
    extern __shared__ float a[];
    int lda = (Kdim + 3) & ~3;
    int t = threadIdx.x;
    int row0 = blockIdx.x * 8;
    for (int r = 0; r < 8; ++r)
        for (int c = t; c < Kdim; c += 256)
            a[r * lda + c] = A[(size_t)(row0 + r) * Kdim + c];
    __syncthreads();
    int co = blockIdx.y * 512 + t * 2;
    float2 bv = *(const float2*)(bias + co);
    float acc[8][2];
#pragma unroll
    for (int r = 0; r < 8; ++r) { acc[r][0] = bv.x; acc[r][1] = bv.y; }
    int ci = 0;
    for (; ci + 4 <= Kdim; ci += 4) {
        float4 av[8];
#pragma unroll
        for (int r = 0; r < 8; ++r) av[r] = *(const float4*)&a[r * lda + ci];
        const float* Wp = W + (size_t)ci * cols + co;
        float2 w0 = *(const float2*)(Wp);
        float2 w1 = *(const float2*)(Wp + (size_t)cols);
        float2 w2 = *(const float2*)(Wp + 2 * (size_t)cols);
        float2 w3 = *(const float2*)(Wp + 3 * (size_t)cols);
#pragma unroll
        for (int r = 0; r < 8; ++r) {
            acc[r][0] = fmaf(av[r].x, w0.x, acc[r][0]); acc[r][1] = fmaf(av[r].x, w0.y, acc[r][1]);
            acc[r][0] = fmaf(av[r].y, w1.x, acc[r][0]); acc[r][1] = fmaf(av[r].y, w1.y, acc[r][1]);
            acc[r][0] = fmaf(av[r].z, w2.x, acc[r][0]); acc[r][1] = fmaf(av[r].z, w2.y, acc[r][1]);
            acc[r][0] = fmaf(av[r].w, w3.x, acc[r][0]); acc[r][1] = fmaf(av[r].w, w3.y, acc[r][1]);
        }
    }
    for (; ci < Kdim; ++ci) {
        float w0 = W[(size_t)ci * cols + co], w1 = W[(size_t)ci * cols + co + 1];
#pragma unroll
        for (int r = 0; r < 8; ++r) {
            float av = a[r * lda + ci];
            acc[r][0] = fmaf(av, w0, acc[r][0]);
            acc[r][1] = fmaf(av, w1, acc[r][1]);
        }
    }
#pragma unroll
    for (int r = 0; r < 8; ++r) {
        float v0 = acc[r][0], v1 = acc[r][1];
        if (act == 1) { v0 = fmaxf(v0, 0.f); v1 = fmaxf(v1, 0.f); }
        else if (act == 2) { v0 = lrelu01(v0); v1 = lrelu01(v1); }
        *(float2*)&C[(size_t)(row0 + r) * cols + co] = make_float2(v0, v1);
    }
}

// ---------------------------------------------------------------- 8) vote aggregation
__global__ void votes_kernel(const float* __restrict__ e, float* __restrict__ z) {
    int o = blockIdx.x * 256 + threadIdx.x;          // 8192 exact
    int b = o >> 10, c = o & 1023;
    const float* eb = e + (size_t)b * SSAMP * 2048;
    float num = 0.f, den = 0.f;
    for (int s = 0; s < SSAMP; ++s) {
        float mean = eb[(size_t)s * 2048 + c];
        float lv = eb[(size_t)s * 2048 + 1024 + c];
        float sd = expf(0.5f * lv);
        num += mean / sd;
        den += 1.f / sd;
    }
    z[o] = num / den;
}

// ---------------------------------------------------------------- 9) u = z @ Wf[0:1024] + b (both decoders)
__global__ void ukern(const float* __restrict__ z, const float* __restrict__ Wf11,
                      const float* __restrict__ bf11, const float* __restrict__ Wf21,
                      const float* __restrict__ bf21, float* __restrict__ u1,
                      float* __restrict__ u2) {
    const float* W = blockIdx.y ? Wf21 : Wf11;
    const float* bs_ = blockIdx.y ? bf21 : bf11;
    float* out = blockIdx.y ? u2 : u1;
    int co = blockIdx.x * 64 + (threadIdx.x & 63);
    int r0 = (threadIdx.x >> 6) * 2;
    float acc0 = bs_[co], acc1 = bs_[co];
    for (int ci = 0; ci < 1024; ++ci) {
        float w = W[(size_t)ci * 512 + co];
        acc0 = fmaf(z[r0 * 1024 + ci], w, acc0);
        acc1 = fmaf(z[(r0 + 1) * 1024 + ci], w, acc1);
    }
    out[r0 * 512 + co] = acc0;
    out[(r0 + 1) * 512 + co] = acc1;
}

// ---------------------------------------------------------------- 10) fold1 first layer: relu(u1 + gx*Wrow1024 + gy*Wrow1025)
__global__ void fold1_kernel(const float* __restrict__ u1, const float* __restrict__ Wf11,
                             float* __restrict__ f1) {
    int o = blockIdx.x * 256 + threadIdx.x;          // 8*2025*512 exact
    int co = o & 511;
    int rg = o >> 9;
    int b = rg / 2025;
    int g = rg - b * 2025;
    int i = g / 45, j = g - i * 45;
    float gx = (j == 44) ? 0.3f : (float)(-0.3 + j * (0.6 / 44.0));
    float gy = (i == 44) ? 0.3f : (float)(-0.3 + i * (0.6 / 44.0));
    float v = u1[(b << 9) + co];
    v = fmaf(gx, Wf11[1024 * 512 + co], v);
    v = fmaf(gy, Wf11[1025 * 512 + co], v);
    f1[o] = fmaxf(v, 0.f);
}

// ---------------------------------------------------------------- 13) fold2 first layer: relu(u2 + sum_j p_j*Wrow(1024+j))
__global__ void fold2_kernel(const float* __restrict__ u2, const float* __restrict__ Wf21,
                             const float* __restrict__ pts, float* __restrict__ f2) {
    int o = blockIdx.x * 256 + threadIdx.x;
    int co = o & 511;
    int rg = o >> 9;
    int b = rg / 2025;
    float p0 = pts[rg * 3 + 0], p1 = pts[rg * 3 + 1], p2 = pts[rg * 3 + 2];
    float v = u2[(b << 9) + co];
    v = fmaf(p0, Wf21[1024 * 512 + co], v);
    v = fmaf(p1, Wf21[1025 * 512 + co], v);
    v = fmaf(p2, Wf21[1026 * 512 + co], v);
    f2[o] = fmaxf(v, 0.f);
}

// ---------------------------------------------------------------- final 512->3 projections
__global__ void smallout_kernel(const float* __restrict__ H, const float* __restrict__ Wf,
                                const float* __restrict__ bf, float* __restrict__ out, int total) {
    int o = blockIdx.x * 256 + threadIdx.x;
    if (o >= total) return;
    int rg = o / 3, c = o - rg * 3;
    const float* h = H + (size_t)rg * 512;
    float a0 = 0.f, a1 = 0.f, a2 = 0.f, a3 = 0.f;
    for (int ci = 0; ci < 512; ci += 4) {
        a0 = fmaf(h[ci + 0], Wf[(ci + 0) * 3 + c], a0);
        a1 = fmaf(h[ci + 1], Wf[(ci + 1) * 3 + c], a1);
        a2 = fmaf(h[ci + 2], Wf[(ci + 2) * 3 + c], a2);
        a3 = fmaf(h[ci + 3], Wf[(ci + 3) * 3 + c], a3);
    }
    out[o] = a0 + a1 + a2 + a3 + bf[c];
}

extern "C" void kernel_launch(void* const* d_in, const int* in_sizes, int n_in,
                              void* d_out, int out_size, void* d_ws, size_t ws_size,
                              hipStream_t stream) {
    const float* pos  = (const float*)d_in[0];
    const float* Wt   = (const float*)d_in[1];
    const float* bt   = (const float*)d_in[2];
    const float* Wc1  = (const float*)d_in[3];
    const float* bc1  = (const float*)d_in[4];
    const float* Wc2  = (const float*)d_in[5];
    const float* bc2  = (const float*)d_in[6];
    const float* Wc3  = (const float*)d_in[7];
    const float* bc3  = (const float*)d_in[8];
    const float* We1  = (const float*)d_in[9];
    const float* be1  = (const float*)d_in[10];
    const float* We2  = (const float*)d_in[11];
    const float* be2  = (const float*)d_in[12];
    const float* Wf11 = (const float*)d_in[13];
    const float* bf11 = (const float*)d_in[14];
    const float* Wf12 = (const float*)d_in[15];
    const float* bf12 = (const float*)d_in[16];
    const float* Wf13 = (const float*)d_in[17];
    const float* bf13 = (const float*)d_in[18];
    const float* Wf21 = (const float*)d_in[19];
    const float* bf21 = (const float*)d_in[20];
    const float* Wf22 = (const float*)d_in[21];
    const float* bf22 = (const float*)d_in[22];
    const float* Wf23 = (const float*)d_in[23];
    const float* bf23 = (const float*)d_in[24];
    float* out = (float*)d_out;

    float* wsf = (float*)d_ws;
    // seg1 lives until votes; f1 (decoder activations) aliases it afterwards.
    size_t off = 0;
    float* x     = wsf + off; off += 2097152;   // [B,N,64]
    float* aggb  = wsf + off; off += 1048576;   // [B,S,512]
    float* encin = wsf + off; off += 1054720;   // [2048,515]
    float* e1    = wsf + off; off += 1048576;   // [2048,512]
    float* e     = wsf + off; off += 4194304;   // [2048,2048]  seg1 end = 9,443,328 floats
    float* f1    = wsf;                         // alias of seg1: [16200,512] = 8,294,400 floats
    off = 9443328;
    float* h12   = wsf + off; off += 8294400;   // [16200,512]
    float* zb    = wsf + off; off += 8192;      // [8,1024]
    float* u1    = wsf + off; off += 4096;
    float* u2    = wsf + off; off += 4096;
    float* pts   = wsf + off; off += 48600;     // fold1 output [16200,3]
    float* newp  = wsf + off; off += 6144;      // [B,S,3]
    int*   fpsix = (int*)(wsf + off); off += 2048;
    int*   nix   = (int*)(wsf + off); off += 262144;

    xform_kernel<<<8192, 256, 0, stream>>>(pos, Wt, bt, x);
    fps_kernel<<<BATCH, 512, 0, stream>>>(pos, fpsix, newp);
    ballq_kernel<<<512, 256, 0, stream>>>(pos, newp, nix);
    pointconv_kernel<<<2048, 256, 0, stream>>>(x, pos, newp, nix, Wc1, bc1, Wc2, bc2, Wc3, bc3, aggb);
    encin_kernel<<<4120, 256, 0, stream>>>(aggb, newp, encin);
    gemm_rb8<<<dim3(256, 1), 256, 516 * 8 * 4, stream>>>(encin, We1, be1, e1, 515, 512, 2);
    gemm_rb8<<<dim3(256, 4), 256, 512 * 8 * 4, stream>>>(e1, We2, be2, e, 512, 2048, 0);
    votes_kernel<<<32, 256, 0, stream>>>(e, zb);
    ukern<<<dim3(8, 2), 256, 0, stream>>>(zb, Wf11, bf11, Wf21, bf21, u1, u2);
    fold1_kernel<<<32400, 256, 0, stream>>>(u1, Wf11, f1);
    gemm_rb8<<<dim3(2025, 1), 256, 512 * 8 * 4, stream>>>(f1, Wf12, bf12, h12, 512, 512, 1);
    smallout_kernel<<<190, 256, 0, stream>>>(h12, Wf13, bf13, pts, 48600);
    fold2_kernel<<<32400, 256, 0, stream>>>(u2, Wf21, pts, f1);
    gemm_rb8<<<dim3(2025, 1), 256, 512 * 8 * 4, stream>>>(f1, Wf22, bf22, h12, 512, 512, 1);
    smallout_kernel<<<190, 256, 0, stream>>>(h12, Wf23, bf23, out, 48600);
}

// Round 3
// 1176.295 us; speedup vs baseline: 1.6606x; 1.4395x over previous
//
#include <hip/hip_runtime.h>
#include <math.h>

#define BATCH 8
#define NPTS 4096
#define SSAMP 256
#define KNBR 128
#define GGRID 2025

typedef __attribute__((ext_vector_type(8))) short bf16x8;
typedef __attribute__((ext_vector_type(4))) float f32x4;
#define MFMA16(a, b, c) __builtin_amdgcn_mfma_f32_16x16x32_bf16((a), (b), (c), 0, 0, 0)

__device__ __forceinline__ float lrelu01(float v) { return v > 0.f ? v : 0.01f * v; }
__device__ __forceinline__ unsigned short f2bf(float f) {
    unsigned u = __float_as_uint(f);
    unsigned r = (u + 0x7FFFu + ((u >> 16) & 1u)) >> 16;
    return (unsigned short)r;
}

// ---------------------------------------------------------------- 0) weight preconvert: WcT[n][k] bf16
// W1T: [64][96]  (Wc1 67x64, K zero-padded to 96)
// W2T: [128][64] (Wc2 64x128)
// W3T: [512][128](Wc3 128x512)
__global__ void preconv_kernel(const float* __restrict__ Wc1, const float* __restrict__ Wc2,
                               const float* __restrict__ Wc3, unsigned short* __restrict__ W1T,
                               unsigned short* __restrict__ W2T, unsigned short* __restrict__ W3T) {
    int o = blockIdx.x * 256 + threadIdx.x;
    const int T1 = 64 * 96, T2 = 128 * 64, T3 = 512 * 128;
    if (o < T1) {
        int n = o / 96, k = o - n * 96;
        W1T[o] = f2bf(k < 67 ? Wc1[k * 64 + n] : 0.f);
    } else if (o < T1 + T2) {
        int p = o - T1;
        int n = p >> 6, k = p & 63;
        W2T[p] = f2bf(Wc2[k * 128 + n]);
    } else if (o < T1 + T2 + T3) {
        int p = o - T1 - T2;
        int n = p >> 7, k = p & 127;
        W3T[p] = f2bf(Wc3[k * 512 + n]);
    }
}

// ---------------------------------------------------------------- 1) x = bf16(lrelu(pos @ Wt + bt))
__global__ void xform_kernel(const float* __restrict__ pos, const float* __restrict__ Wt,
                             const float* __restrict__ bt, unsigned short* __restrict__ x) {
    int o = blockIdx.x * 256 + threadIdx.x;          // B*N*64 = 2,097,152 exact
    int c = o & 63, p = o >> 6;
    const float* pr = pos + (size_t)p * 3;
    float v = fmaf(pr[2], Wt[128 + c], fmaf(pr[1], Wt[64 + c], fmaf(pr[0], Wt[c], bt[c])));
    x[o] = f2bf(lrelu01(v));
}

// ---------------------------------------------------------------- 2) FPS (one block per cloud)
__global__ void __launch_bounds__(512) fps_kernel(const float* __restrict__ pos,
                                                  int* __restrict__ fpsidx,
                                                  float* __restrict__ newpos) {
    int b = blockIdx.x, t = threadIdx.x;
    const float* P = pos + (size_t)b * NPTS * 3;
    float px[8], py[8], pz[8], mind[8];
#pragma unroll
    for (int j = 0; j < 8; ++j) {
        int n = t + 512 * j;
        px[j] = P[n * 3 + 0]; py[j] = P[n * 3 + 1]; pz[j] = P[n * 3 + 2];
        mind[j] = 3.402823466e+38f;
    }
    __shared__ float cpt[3];
    __shared__ unsigned long long red[8];
    if (t == 0) {
        fpsidx[b * SSAMP] = 0;
        newpos[(size_t)b * SSAMP * 3 + 0] = P[0];
        newpos[(size_t)b * SSAMP * 3 + 1] = P[1];
        newpos[(size_t)b * SSAMP * 3 + 2] = P[2];
        cpt[0] = P[0]; cpt[1] = P[1]; cpt[2] = P[2];
    }
    __syncthreads();
    for (int s = 1; s < SSAMP; ++s) {
        float cx = cpt[0], cy = cpt[1], cz = cpt[2];
        unsigned long long best = 0ull;
#pragma unroll
        for (int j = 0; j < 8; ++j) {
            float dx = __fsub_rn(px[j], cx), dy = __fsub_rn(py[j], cy), dz = __fsub_rn(pz[j], cz);
            float d = __fadd_rn(__fadd_rn(__fmul_rn(dx, dx), __fmul_rn(dy, dy)), __fmul_rn(dz, dz));
            mind[j] = fminf(mind[j], d);
            unsigned long long key = ((unsigned long long)__float_as_uint(mind[j]) << 32)
                                   | (unsigned int)(~(unsigned int)(t + 512 * j));
            if (key > best) best = key;
        }
#pragma unroll
        for (int off = 32; off > 0; off >>= 1) {
            unsigned long long o = __shfl_down(best, off, 64);
            if (o > best) best = o;
        }
        if ((t & 63) == 0) red[t >> 6] = best;
        __syncthreads();
        if (t < 64) {
            unsigned long long bb = (t < 8) ? red[t] : 0ull;
#pragma unroll
            for (int off = 4; off > 0; off >>= 1) {
                unsigned long long o = __shfl_down(bb, off, 64);
                if (o > bb) bb = o;
            }
            if (t == 0) {
                int nx = (int)(~(unsigned int)(bb & 0xFFFFFFFFull));
                fpsidx[b * SSAMP + s] = nx;
                float X = P[(size_t)nx * 3], Y = P[(size_t)nx * 3 + 1], Z = P[(size_t)nx * 3 + 2];
                newpos[((size_t)b * SSAMP + s) * 3 + 0] = X;
                newpos[((size_t)b * SSAMP + s) * 3 + 1] = Y;
                newpos[((size_t)b * SSAMP + s) * 3 + 2] = Z;
                cpt[0] = X; cpt[1] = Y; cpt[2] = Z;
            }
        }
        __syncthreads();
    }
}

// ---------------------------------------------------------------- 3) radius ball query (one wave per (b,s))
__global__ void __launch_bounds__(256) ballq_kernel(const float* __restrict__ pos,
                                                    const float* __restrict__ newpos,
                                                    int* __restrict__ nidx) {
    int w = blockIdx.x * 4 + (threadIdx.x >> 6);     // 0..2047 = b*256+s
    int lane = threadIdx.x & 63;
    int b = w >> 8;
    const float* P = pos + (size_t)b * NPTS * 3;
    float qx = newpos[w * 3 + 0], qy = newpos[w * 3 + 1], qz = newpos[w * 3 + 2];
    int* out = nidx + (size_t)w * KNBR;
    int base = 0;
    for (int c = 0; c < 64; ++c) {
        int n = c * 64 + lane;
        float dx = __fsub_rn(P[n * 3 + 0], qx);
        float dy = __fsub_rn(P[n * 3 + 1], qy);
        float dz = __fsub_rn(P[n * 3 + 2], qz);
        float d2 = __fadd_rn(__fadd_rn(__fmul_rn(dx, dx), __fmul_rn(dy, dy)), __fmul_rn(dz, dz));
        bool in = (d2 <= 0.04f);
        unsigned long long mask = __ballot(in);
        if (in) {
            int p = base + __popcll(mask & ((1ull << lane) - 1ull));
            if (p < KNBR) out[p] = n;
        }
        base += __popcll(mask);
        if (base >= KNBR) break;
    }
    for (int p = base + lane; p < KNBR; p += 64) out[p] = -1;
}

// ---------------------------------------------------------------- 4) fused PointConv via bf16 MFMA (one block per (b,s))
// Per-block GEMMs: L1 128x64 K=96(pad), L2 128x128 K=64, L3 128x512 K=128.
// Wave w owns M-tiles {2w,2w+1}. C/D layout: col=lane&15,row=quad*4+reg (verified m89/m91).
// lrelu is monotonic -> masked max on raw acc, bias+lrelu applied once per channel.
__global__ void __launch_bounds__(256, 2) pointconv_kernel(
    const unsigned short* __restrict__ xbf, const float* __restrict__ pos,
    const float* __restrict__ newpos, const int* __restrict__ nidx,
    const unsigned short* __restrict__ W1T, const unsigned short* __restrict__ W2T,
    const unsigned short* __restrict__ W3T,
    const float* __restrict__ bc1, const float* __restrict__ bc2, const float* __restrict__ bc3,
    float* __restrict__ agg) {
    __shared__ __align__(16) unsigned char smem[34816 + 18432 + 512 + 8192];
    unsigned short* featl = (unsigned short*)smem;           // [128][104] bf16 (phase A)
    unsigned short* h2    = (unsigned short*)smem;           // [128][136] bf16 (aliases feat)
    unsigned short* h1    = (unsigned short*)(smem + 34816); // [128][72] bf16
    int*   vld  = (int*)(smem + 34816 + 18432);              // [128]
    float* mred = (float*)(smem + 34816 + 18432 + 512);      // [4][512]

    int bs = blockIdx.x, b = bs >> 8, t = threadIdx.x;
    int wave = t >> 6, lane = t & 63, quad = lane >> 4, l16 = lane & 15;
    const float* npp = newpos + (size_t)bs * 3;
    float q0 = npp[0], q1 = npp[1], q2 = npp[2];
    if (t < 128) vld[t] = nidx[(size_t)bs * KNBR + t];
    __syncthreads();

    int vbits = 0;
#pragma unroll
    for (int i = 0; i < 2; ++i)
#pragma unroll
        for (int reg = 0; reg < 4; ++reg)
            if (vld[(2 * wave + i) * 16 + quad * 4 + reg] >= 0) vbits |= 1 << (i * 4 + reg);

    // ---- Phase A: stage feat bf16 [128][104], cols 0..63 = x_j, 64..66 = pos_j - pos_i, 67..95 = 0
#pragma unroll 4
    for (int it = 0; it < 48; ++it) {
        int e = t + it * 256;                 // e < 12288 = 128*96
        int row = e / 96, c = e - row * 96;
        int n = vld[row];
        unsigned short v = 0;
        if (n >= 0) {
            if (c < 64) v = xbf[((size_t)b * NPTS + n) * 64 + c];
            else if (c < 67) {
                int d = c - 64;
                float pv = pos[((size_t)b * NPTS + n) * 3 + d];
                float qv = (d == 0) ? q0 : (d == 1) ? q1 : q2;
                v = f2bf(__fsub_rn(pv, qv));
            }
        }
        featl[row * 104 + c] = v;
    }
    __syncthreads();

    // ---- Layer 1 MFMA: M=128, N=64, K=96
    {
        f32x4 acc[2][4];
#pragma unroll
        for (int i = 0; i < 2; ++i)
#pragma unroll
            for (int nt = 0; nt < 4; ++nt) acc[i][nt] = (f32x4){0.f, 0.f, 0.f, 0.f};
#pragma unroll
        for (int ks = 0; ks < 3; ++ks) {
            bf16x8 afr[2];
#pragma unroll
            for (int i = 0; i < 2; ++i)
                afr[i] = *(const bf16x8*)&featl[((2 * wave + i) * 16 + l16) * 104 + ks * 32 + quad * 8];
#pragma unroll
            for (int nt = 0; nt < 4; ++nt) {
                bf16x8 bfr = *(const bf16x8*)(W1T + (nt * 16 + l16) * 96 + ks * 32 + quad * 8);
                acc[0][nt] = MFMA16(afr[0], bfr, acc[0][nt]);
                acc[1][nt] = MFMA16(afr[1], bfr, acc[1][nt]);
            }
        }
#pragma unroll
        for (int i = 0; i < 2; ++i)
#pragma unroll
            for (int nt = 0; nt < 4; ++nt) {
                int col = nt * 16 + l16;
                float bias = bc1[col];
#pragma unroll
                for (int reg = 0; reg < 4; ++reg) {
                    int row = (2 * wave + i) * 16 + quad * 4 + reg;
                    h1[row * 72 + col] = f2bf(lrelu01(acc[i][nt][reg] + bias));
                }
            }
    }
    __syncthreads();

    // ---- Layer 2 MFMA: M=128, N=128, K=64  (h2 output aliases feat region)
    {
        f32x4 acc[2][8];
#pragma unroll
        for (int i = 0; i < 2; ++i)
#pragma unroll
            for (int nt = 0; nt < 8; ++nt) acc[i][nt] = (f32x4){0.f, 0.f, 0.f, 0.f};
#pragma unroll
        for (int ks = 0; ks < 2; ++ks) {
            bf16x8 afr[2];
#pragma unroll
            for (int i = 0; i < 2; ++i)
                afr[i] = *(const bf16x8*)&h1[((2 * wave + i) * 16 + l16) * 72 + ks * 32 + quad * 8];
#pragma unroll
            for (int nt = 0; nt < 8; ++nt) {
                bf16x8 bfr = *(const bf16x8*)(W2T + (nt * 16 + l16) * 64 + ks * 32 + quad * 8);
                acc[0][nt] = MFMA16(afr[0], bfr, acc[0][nt]);
                acc[1][nt] = MFMA16(afr[1], bfr, acc[1][nt]);
            }
        }
        __syncthreads();   // everyone done reading feat/h1 before h2 overwrites feat region
#pragma unroll
        for (int i = 0; i < 2; ++i)
#pragma unroll
            for (int nt = 0; nt < 8; ++nt) {
                int col = nt * 16 + l16;
                float bias = bc2[col];
#pragma unroll
                for (int reg = 0; reg < 4; ++reg) {
                    int row = (2 * wave + i) * 16 + quad * 4 + reg;
                    h2[row * 136 + col] = f2bf(lrelu01(acc[i][nt][reg] + bias));
                }
            }
    }
    __syncthreads();

    // ---- Layer 3 MFMA: M=128, N=512 (4 chunks of 128), K=128; masked max over valid rows
    for (int c3 = 0; c3 < 4; ++c3) {
        f32x4 acc[2][8];
#pragma unroll
        for (int i = 0; i < 2; ++i)
#pragma unroll
            for (int nt = 0; nt < 8; ++nt) acc[i][nt] = (f32x4){0.f, 0.f, 0.f, 0.f};
#pragma unroll
        for (int ks = 0; ks < 4; ++ks) {
            bf16x8 afr[2];
#pragma unroll
            for (int i = 0; i < 2; ++i)
                afr[i] = *(const bf16x8*)&h2[((2 * wave + i) * 16 + l16) * 136 + ks * 32 + quad * 8];
#pragma unroll
            for (int nt = 0; nt < 8; ++nt) {
                bf16x8 bfr = *(const bf16x8*)(W3T + ((size_t)((c3 * 8 + nt) * 16 + l16)) * 128 + ks * 32 + quad * 8);
                acc[0][nt] = MFMA16(afr[0], bfr, acc[0][nt]);
                acc[1][nt] = MFMA16(afr[1], bfr, acc[1][nt]);
            }
        }
#pragma unroll
        for (int nt = 0; nt < 8; ++nt) {
            float vmax = -3.402823466e+38f;
#pragma unroll
            for (int i = 0; i < 2; ++i)
#pragma unroll
                for (int reg = 0; reg < 4; ++reg)
                    if (vbits & (1 << (i * 4 + reg))) vmax = fmaxf(vmax, acc[i][nt][reg]);
            vmax = fmaxf(vmax, __shfl_xor(vmax, 16));
            vmax = fmaxf(vmax, __shfl_xor(vmax, 32));
            if (lane < 16) mred[wave * 512 + (c3 * 8 + nt) * 16 + l16] = vmax;
        }
    }
    __syncthreads();
    for (int c = t; c < 512; c += 256) {
        float v = fmaxf(fmaxf(mred[c], mred[512 + c]), fmaxf(mred[1024 + c], mred[1536 + c]));
        agg[(size_t)bs * 512 + c] = lrelu01(v + bc3[c]);
    }
}

// ---------------------------------------------------------------- 5) encin = cat[agg, newpos]
__global__ void encin_kernel(const float* __restrict__ agg, const float* __restrict__ newpos,
                             float* __restrict__ encin) {
    int o = blockIdx.x * 256 + threadIdx.x;
    if (o >= 2048 * 515) return;
    int r = o / 515, c = o - r * 515;
    encin[o] = (c < 512) ? agg[r * 512 + c] : newpos[r * 3 + (c - 512)];
}

// ---------------------------------------------------------------- generic GEMM: C = act(A@W + b), 8 rows x 512 cols per block
__global__ void __launch_bounds__(256) gemm_rb8(const float* __restrict__ A,
                                                const float* __restrict__ W,
                                                const float* __restrict__ bias,
                                                float* __restrict__ C,
                                                int Kdim, int cols, int act) {
    extern __shared__ float a[];
    int lda = (Kdim + 3) & ~3;
    int t = threadIdx.x;
    int row0 = blockIdx.x * 8;
    for (int r = 0; r < 8; ++r)
        for (int c = t; c < Kdim; c += 256)
            a[r * lda + c] = A[(size_t)(row0 + r) * Kdim + c];
    __syncthreads();
    int co = blockIdx.y * 512 + t * 2;
    float2 bv = *(const float2*)(bias + co);
    float acc[8][2];
#pragma unroll
    for (int r = 0; r < 8; ++r) { acc[r][0] = bv.x; acc[r][1] = bv.y; }
    int ci = 0;
    for (; ci + 4 <= Kdim; ci += 4) {
        float4 av[8];
#pragma unroll
        for (int r = 0; r < 8; ++r) av[r] = *(const float4*)&a[r * lda + ci];
        const float* Wp = W + (size_t)ci * cols + co;
        float2 w0 = *(const float2*)(Wp);
        float2 w1 = *(const float2*)(Wp + (size_t)cols);
        float2 w2 = *(const float2*)(Wp + 2 * (size_t)cols);
        float2 w3 = *(const float2*)(Wp + 3 * (size_t)cols);
#pragma unroll
        for (int r = 0; r < 8; ++r) {
            acc[r][0] = fmaf(av[r].x, w0.x, acc[r][0]); acc[r][1] = fmaf(av[r].x, w0.y, acc[r][1]);
            acc[r][0] = fmaf(av[r].y, w1.x, acc[r][0]); acc[r][1] = fmaf(av[r].y, w1.y, acc[r][1]);
            acc[r][0] = fmaf(av[r].z, w2.x, acc[r][0]); acc[r][1] = fmaf(av[r].z, w2.y, acc[r][1]);
            acc[r][0] = fmaf(av[r].w, w3.x, acc[r][0]); acc[r][1] = fmaf(av[r].w, w3.y, acc[r][1]);
        }
    }
    for (; ci < Kdim; ++ci) {
        float w0 = W[(size_t)ci * cols + co], w1 = W[(size_t)ci * cols + co + 1];
#pragma unroll
        for (int r = 0; r < 8; ++r) {
            float av = a[r * lda + ci];
            acc[r][0] = fmaf(av, w0, acc[r][0]);
            acc[r][1] = fmaf(av, w1, acc[r][1]);
        }
    }
#pragma unroll
    for (int r = 0; r < 8; ++r) {
        float v0 = acc[r][0], v1 = acc[r][1];
        if (act == 1) { v0 = fmaxf(v0, 0.f); v1 = fmaxf(v1, 0.f); }
        else if (act == 2) { v0 = lrelu01(v0); v1 = lrelu01(v1); }
        *(float2*)&C[(size_t)(row0 + r) * cols + co] = make_float2(v0, v1);
    }
}

// ---------------------------------------------------------------- 8) vote aggregation
__global__ void votes_kernel(const float* __restrict__ e, float* __restrict__ z) {
    int o = blockIdx.x * 256 + threadIdx.x;          // 8192 exact
    int b = o >> 10, c = o & 1023;
    const float* eb = e + (size_t)b * SSAMP * 2048;
    float num = 0.f, den = 0.f;
    for (int s = 0; s < SSAMP; ++s) {
        float mean = eb[(size_t)s * 2048 + c];
        float lv = eb[(size_t)s * 2048 + 1024 + c];
        float sd = expf(0.5f * lv);
        num += mean / sd;
        den += 1.f / sd;
    }
    z[o] = num / den;
}

// ---------------------------------------------------------------- 9) u = z @ Wf[0:1024] + b (both decoders)
__global__ void ukern(const float* __restrict__ z, const float* __restrict__ Wf11,
                      const float* __restrict__ bf11, const float* __restrict__ Wf21,
                      const float* __restrict__ bf21, float* __restrict__ u1,
                      float* __restrict__ u2) {
    const float* W = blockIdx.y ? Wf21 : Wf11;
    const float* bs_ = blockIdx.y ? bf21 : bf11;
    float* out = blockIdx.y ? u2 : u1;
    int co = blockIdx.x * 64 + (threadIdx.x & 63);
    int r0 = (threadIdx.x >> 6) * 2;
    float acc0 = bs_[co], acc1 = bs_[co];
    for (int ci = 0; ci < 1024; ++ci) {
        float w = W[(size_t)ci * 512 + co];
        acc0 = fmaf(z[r0 * 1024 + ci], w, acc0);
        acc1 = fmaf(z[(r0 + 1) * 1024 + ci], w, acc1);
    }
    out[r0 * 512 + co] = acc0;
    out[(r0 + 1) * 512 + co] = acc1;
}

// ---------------------------------------------------------------- 10) fold1 first layer
__global__ void fold1_kernel(const float* __restrict__ u1, const float* __restrict__ Wf11,
                             float* __restrict__ f1) {
    int o = blockIdx.x * 256 + threadIdx.x;          // 8*2025*512 exact
    int co = o & 511;
    int rg = o >> 9;
    int b = rg / 2025;
    int g = rg - b * 2025;
    int i = g / 45, j = g - i * 45;
    float gx = (j == 44) ? 0.3f : (float)(-0.3 + j * (0.6 / 44.0));
    float gy = (i == 44) ? 0.3f : (float)(-0.3 + i * (0.6 / 44.0));
    float v = u1[(b << 9) + co];
    v = fmaf(gx, Wf11[1024 * 512 + co], v);
    v = fmaf(gy, Wf11[1025 * 512 + co], v);
    f1[o] = fmaxf(v, 0.f);
}

// ---------------------------------------------------------------- 13) fold2 first layer
__global__ void fold2_kernel(const float* __restrict__ u2, const float* __restrict__ Wf21,
                             const float* __restrict__ pts, float* __restrict__ f2) {
    int o = blockIdx.x * 256 + threadIdx.x;
    int co = o & 511;
    int rg = o >> 9;
    int b = rg / 2025;
    float p0 = pts[rg * 3 + 0], p1 = pts[rg * 3 + 1], p2 = pts[rg * 3 + 2];
    float v = u2[(b << 9) + co];
    v = fmaf(p0, Wf21[1024 * 512 + co], v);
    v = fmaf(p1, Wf21[1025 * 512 + co], v);
    v = fmaf(p2, Wf21[1026 * 512 + co], v);
    f2[o] = fmaxf(v, 0.f);
}

// ---------------------------------------------------------------- final 512->3 projections
__global__ void smallout_kernel(const float* __restrict__ H, const float* __restrict__ Wf,
                                const float* __restrict__ bf, float* __restrict__ out, int total) {
    int o = blockIdx.x * 256 + threadIdx.x;
    if (o >= total) return;
    int rg = o / 3, c = o - rg * 3;
    const float* h = H + (size_t)rg * 512;
    float a0 = 0.f, a1 = 0.f, a2 = 0.f, a3 = 0.f;
    for (int ci = 0; ci < 512; ci += 4) {
        a0 = fmaf(h[ci + 0], Wf[(ci + 0) * 3 + c], a0);
        a1 = fmaf(h[ci + 1], Wf[(ci + 1) * 3 + c], a1);
        a2 = fmaf(h[ci + 2], Wf[(ci + 2) * 3 + c], a2);
        a3 = fmaf(h[ci + 3], Wf[(ci + 3) * 3 + c], a3);
    }
    out[o] = a0 + a1 + a2 + a3 + bf[c];
}

extern "C" void kernel_launch(void* const* d_in, const int* in_sizes, int n_in,
                              void* d_out, int out_size, void* d_ws, size_t ws_size,
                              hipStream_t stream) {
    const float* pos  = (const float*)d_in[0];
    const float* Wt   = (const float*)d_in[1];
    const float* bt   = (const float*)d_in[2];
    const float* Wc1  = (const float*)d_in[3];
    const float* bc1  = (const float*)d_in[4];
    const float* Wc2  = (const float*)d_in[5];
    const float* bc2  = (const float*)d_in[6];
    const float* Wc3  = (const float*)d_in[7];
    const float* bc3  = (const float*)d_in[8];
    const float* We1  = (const float*)d_in[9];
    const float* be1  = (const float*)d_in[10];
    const float* We2  = (const float*)d_in[11];
    const float* be2  = (const float*)d_in[12];
    const float* Wf11 = (const float*)d_in[13];
    const float* bf11 = (const float*)d_in[14];
    const float* Wf12 = (const float*)d_in[15];
    const float* bf12 = (const float*)d_in[16];
    const float* Wf13 = (const float*)d_in[17];
    const float* bf13 = (const float*)d_in[18];
    const float* Wf21 = (const float*)d_in[19];
    const float* bf21 = (const float*)d_in[20];
    const float* Wf22 = (const float*)d_in[21];
    const float* bf22 = (const float*)d_in[22];
    const float* Wf23 = (const float*)d_in[23];
    const float* bf23 = (const float*)d_in[24];
    float* out = (float*)d_out;

    float* wsf = (float*)d_ws;
    size_t off = 0;
    float* xreg  = wsf + off; off += 2097152;   // x as bf16 [B,N,64] (uses 1/2 of region)
    float* aggb  = wsf + off; off += 1048576;   // [B,S,512]
    float* encin = wsf + off; off += 1054720;   // [2048,515]
    float* e1    = wsf + off; off += 1048576;   // [2048,512]
    float* e     = wsf + off; off += 4194304;   // [2048,2048]  seg1 end = 9,443,328 floats
    float* f1    = wsf;                         // alias of seg1: [16200,512]
    off = 9443328;
    float* h12   = wsf + off; off += 8294400;   // [16200,512]
    float* zb    = wsf + off; off += 8192;      // [8,1024]
    float* u1    = wsf + off; off += 4096;
    float* u2    = wsf + off; off += 4096;
    float* pts   = wsf + off; off += 48600;     // fold1 output [16200,3]
    float* newp  = wsf + off; off += 6144;      // [B,S,3]
    int*   fpsix = (int*)(wsf + off); off += 2048;
    int*   nix   = (int*)(wsf + off); off += 262144;
    unsigned short* W1T = (unsigned short*)(wsf + off); off += 3072;   // 64*96 bf16
    unsigned short* W2T = (unsigned short*)(wsf + off); off += 4096;   // 128*64 bf16
    unsigned short* W3T = (unsigned short*)(wsf + off); off += 32768;  // 512*128 bf16
    unsigned short* xbf = (unsigned short*)xreg;

    preconv_kernel<<<312, 256, 0, stream>>>(Wc1, Wc2, Wc3, W1T, W2T, W3T);
    xform_kernel<<<8192, 256, 0, stream>>>(pos, Wt, bt, xbf);
    fps_kernel<<<BATCH, 512, 0, stream>>>(pos, fpsix, newp);
    ballq_kernel<<<512, 256, 0, stream>>>(pos, newp, nix);
    pointconv_kernel<<<2048, 256, 0, stream>>>(xbf, pos, newp, nix, W1T, W2T, W3T,
                                               bc1, bc2, bc3, aggb);
    encin_kernel<<<4120, 256, 0, stream>>>(aggb, newp, encin);
    gemm_rb8<<<dim3(256, 1), 256, 516 * 8 * 4, stream>>>(encin, We1, be1, e1, 515, 512, 2);
    gemm_rb8<<<dim3(256, 4), 256, 512 * 8 * 4, stream>>>(e1, We2, be2, e, 512, 2048, 0);
    votes_kernel<<<32, 256, 0, stream>>>(e, zb);
    ukern<<<dim3(8, 2), 256, 0, stream>>>(zb, Wf11, bf11, Wf21, bf21, u1, u2);
    fold1_kernel<<<32400, 256, 0, stream>>>(u1, Wf11, f1);
    gemm_rb8<<<dim3(2025, 1), 256, 512 * 8 * 4, stream>>>(f1, Wf12, bf12, h12, 512, 512, 1);
    smallout_kernel<<<190, 256, 0, stream>>>(h12, Wf13, bf13, pts, 48600);
    fold2_kernel<<<32400, 256, 0, stream>>>(u2, Wf21, pts, f1);
    gemm_rb8<<<dim3(2025, 1), 256, 512 * 8 * 4, stream>>>(f1, Wf22, bf22, h12, 512, 512, 1);
    smallout_kernel<<<190, 256, 0, stream>>>(h12, Wf23, bf23, out, 48600);
}

// Round 4
// 841.409 us; speedup vs baseline: 2.3215x; 1.3980x over previous
//
#include <hip/hip_runtime.h>
#include <math.h>

#define BATCH 8
#define NPTS 4096
#define SSAMP 256
#define KNBR 128
#define GGRID 2025

typedef __attribute__((ext_vector_type(8))) short bf16x8;
typedef __attribute__((ext_vector_type(8))) unsigned short u16x8;
typedef __attribute__((ext_vector_type(4))) float f32x4;
#define MFMA16(a, b, c) __builtin_amdgcn_mfma_f32_16x16x32_bf16((a), (b), (c), 0, 0, 0)

__device__ __forceinline__ float lrelu01(float v) { return v > 0.f ? v : 0.01f * v; }
__device__ __forceinline__ unsigned short f2bf(float f) {
    unsigned u = __float_as_uint(f);
    unsigned r = (u + 0x7FFFu + ((u >> 16) & 1u)) >> 16;
    return (unsigned short)r;
}

// ---------------------------------------------------------------- 0) weight preconvert to bf16 [n][k]
__global__ void preconv_kernel(const float* __restrict__ Wc1, const float* __restrict__ Wc2,
                               const float* __restrict__ Wc3, const float* __restrict__ We1,
                               const float* __restrict__ We2, const float* __restrict__ Wf12,
                               const float* __restrict__ Wf22,
                               unsigned short* __restrict__ W1T, unsigned short* __restrict__ W2T,
                               unsigned short* __restrict__ W3T, unsigned short* __restrict__ We1T,
                               unsigned short* __restrict__ We2T, unsigned short* __restrict__ Wf12T,
                               unsigned short* __restrict__ Wf22T) {
    int o = blockIdx.x * 256 + threadIdx.x;
    const int S1 = 6144, S2 = 8192, S3 = 65536, S4 = 294912, S5 = 1048576, S6 = 262144;
    if (o < S1) { int n = o / 96, k = o - n * 96; W1T[o] = f2bf(k < 67 ? Wc1[k * 64 + n] : 0.f); return; }
    o -= S1;
    if (o < S2) { int n = o >> 6, k = o & 63; W2T[o] = f2bf(Wc2[k * 128 + n]); return; }
    o -= S2;
    if (o < S3) { int n = o >> 7, k = o & 127; W3T[o] = f2bf(Wc3[k * 512 + n]); return; }
    o -= S3;
    if (o < S4) { int n = o / 576, k = o - n * 576; We1T[o] = f2bf(k < 515 ? We1[k * 512 + n] : 0.f); return; }
    o -= S4;
    if (o < S5) { int n = o >> 9, k = o & 511; We2T[o] = f2bf(We2[k * 2048 + n]); return; }
    o -= S5;
    if (o < S6) { int n = o >> 9, k = o & 511; Wf12T[o] = f2bf(Wf12[k * 512 + n]); return; }
    o -= S6;
    { int n = o >> 9, k = o & 511; Wf22T[o] = f2bf(Wf22[k * 512 + n]); }
}

// ---------------------------------------------------------------- 1) x = bf16(lrelu(pos @ Wt + bt))
__global__ void xform_kernel(const float* __restrict__ pos, const float* __restrict__ Wt,
                             const float* __restrict__ bt, unsigned short* __restrict__ x) {
    int o = blockIdx.x * 256 + threadIdx.x;          // B*N*64 exact
    int c = o & 63, p = o >> 6;
    const float* pr = pos + (size_t)p * 3;
    float v = fmaf(pr[2], Wt[128 + c], fmaf(pr[1], Wt[64 + c], fmaf(pr[0], Wt[c], bt[c])));
    x[o] = f2bf(lrelu01(v));
}

// ---------------------------------------------------------------- 2) FPS (one block per cloud, 1 barrier/step)
__global__ void __launch_bounds__(512) fps_kernel(const float* __restrict__ pos,
                                                  int* __restrict__ fpsidx,
                                                  float* __restrict__ newpos) {
    int b = blockIdx.x, t = threadIdx.x;
    const float* P = pos + (size_t)b * NPTS * 3;
    float px[8], py[8], pz[8], mind[8];
#pragma unroll
    for (int j = 0; j < 8; ++j) {
        int n = t + 512 * j;
        px[j] = P[n * 3 + 0]; py[j] = P[n * 3 + 1]; pz[j] = P[n * 3 + 2];
        mind[j] = 3.402823466e+38f;
    }
    __shared__ unsigned long long red[2][8];
    float cx = P[0], cy = P[1], cz = P[2];
    if (t == 0) {
        fpsidx[b * SSAMP] = 0;
        newpos[(size_t)b * SSAMP * 3 + 0] = cx;
        newpos[(size_t)b * SSAMP * 3 + 1] = cy;
        newpos[(size_t)b * SSAMP * 3 + 2] = cz;
    }
    for (int s = 1; s < SSAMP; ++s) {
        unsigned long long best = 0ull;
#pragma unroll
        for (int j = 0; j < 8; ++j) {
            float dx = __fsub_rn(px[j], cx), dy = __fsub_rn(py[j], cy), dz = __fsub_rn(pz[j], cz);
            float d = __fadd_rn(__fadd_rn(__fmul_rn(dx, dx), __fmul_rn(dy, dy)), __fmul_rn(dz, dz));
            mind[j] = fminf(mind[j], d);
            unsigned long long key = ((unsigned long long)__float_as_uint(mind[j]) << 32)
                                   | (unsigned int)(~(unsigned int)(t + 512 * j));
            if (key > best) best = key;
        }
#pragma unroll
        for (int off = 32; off > 0; off >>= 1) {
            unsigned long long o = __shfl_down(best, off, 64);
            if (o > best) best = o;
        }
        if ((t & 63) == 0) red[s & 1][t >> 6] = best;
        __syncthreads();
        unsigned long long bb = red[s & 1][0];
#pragma unroll
        for (int k = 1; k < 8; ++k) { unsigned long long o = red[s & 1][k]; if (o > bb) bb = o; }
        int nx = (int)(~(unsigned int)(bb & 0xFFFFFFFFull));
        cx = P[(size_t)nx * 3]; cy = P[(size_t)nx * 3 + 1]; cz = P[(size_t)nx * 3 + 2];
        if (t == 0) {
            fpsidx[b * SSAMP + s] = nx;
            newpos[((size_t)b * SSAMP + s) * 3 + 0] = cx;
            newpos[((size_t)b * SSAMP + s) * 3 + 1] = cy;
            newpos[((size_t)b * SSAMP + s) * 3 + 2] = cz;
        }
    }
}

// ---------------------------------------------------------------- 3) radius ball query (one wave per (b,s))
__global__ void __launch_bounds__(256) ballq_kernel(const float* __restrict__ pos,
                                                    const float* __restrict__ newpos,
                                                    int* __restrict__ nidx) {
    int w = blockIdx.x * 4 + (threadIdx.x >> 6);
    int lane = threadIdx.x & 63;
    int b = w >> 8;
    const float* P = pos + (size_t)b * NPTS * 3;
    float qx = newpos[w * 3 + 0], qy = newpos[w * 3 + 1], qz = newpos[w * 3 + 2];
    int* out = nidx + (size_t)w * KNBR;
    int base = 0;
    for (int c = 0; c < 64; ++c) {
        int n = c * 64 + lane;
        float dx = __fsub_rn(P[n * 3 + 0], qx);
        float dy = __fsub_rn(P[n * 3 + 1], qy);
        float dz = __fsub_rn(P[n * 3 + 2], qz);
        float d2 = __fadd_rn(__fadd_rn(__fmul_rn(dx, dx), __fmul_rn(dy, dy)), __fmul_rn(dz, dz));
        bool in = (d2 <= 0.04f);
        unsigned long long mask = __ballot(in);
        if (in) {
            int p = base + __popcll(mask & ((1ull << lane) - 1ull));
            if (p < KNBR) out[p] = n;
        }
        base += __popcll(mask);
        if (base >= KNBR) break;
    }
    for (int p = base + lane; p < KNBR; p += 64) out[p] = -1;
}

// ---------------------------------------------------------------- 4) fused PointConv via bf16 MFMA + encin epilogue
// LDS 53760 B -> 3 blocks/CU (mred aliases h1). Phase-A staging fully vectorized.
__global__ void __launch_bounds__(256, 3) pointconv_kernel(
    const unsigned short* __restrict__ xbf, const float* __restrict__ pos,
    const float* __restrict__ newpos, const int* __restrict__ nidx,
    const unsigned short* __restrict__ W1T, const unsigned short* __restrict__ W2T,
    const unsigned short* __restrict__ W3T,
    const float* __restrict__ bc1, const float* __restrict__ bc2, const float* __restrict__ bc3,
    unsigned short* __restrict__ encin) {
    __shared__ __align__(16) unsigned char smem[53760];
    unsigned short* featl = (unsigned short*)smem;           // [128][104] bf16 (phase A)
    unsigned short* h2    = (unsigned short*)smem;           // [128][136] bf16 (aliases feat)
    unsigned short* h1    = (unsigned short*)(smem + 34816); // [128][72] bf16
    float* mred = (float*)(smem + 34816);                    // [4][512] fp32 (aliases h1, used in L3)
    int*   vld  = (int*)(smem + 53248);                      // [128]

    int bs = blockIdx.x, b = bs >> 8, t = threadIdx.x;
    int wave = t >> 6, lane = t & 63, quad = lane >> 4, l16 = lane & 15;
    const float* npp = newpos + (size_t)bs * 3;
    float q0 = npp[0], q1 = npp[1], q2 = npp[2];
    if (t < 128) vld[t] = nidx[(size_t)bs * KNBR + t];
    __syncthreads();

    int vbits = 0;
#pragma unroll
    for (int i = 0; i < 2; ++i)
#pragma unroll
        for (int reg = 0; reg < 4; ++reg)
            if (vld[(2 * wave + i) * 16 + quad * 4 + reg] >= 0) vbits |= 1 << (i * 4 + reg);

    // ---- Phase A: vectorized staging, thread pair per row
    {
        int sr = t >> 1, sh = t & 1;
        int n = vld[sr];
        int ns = n < 0 ? 0 : n;
        const u16x8* src = (const u16x8*)(xbf + ((size_t)b * NPTS + ns) * 64);
        u16x8 z8 = {0, 0, 0, 0, 0, 0, 0, 0};
        if (sh == 0) {
#pragma unroll
            for (int j = 0; j < 6; ++j)
                *(u16x8*)&featl[sr * 104 + j * 8] = (n >= 0) ? src[j] : z8;
        } else {
#pragma unroll
            for (int j = 0; j < 2; ++j)
                *(u16x8*)&featl[sr * 104 + 48 + j * 8] = (n >= 0) ? src[6 + j] : z8;
            const float* pp = pos + ((size_t)b * NPTS + ns) * 3;
            u16x8 dv = z8;
            if (n >= 0) {
                dv[0] = (short)f2bf(__fsub_rn(pp[0], q0));
                dv[1] = (short)f2bf(__fsub_rn(pp[1], q1));
                dv[2] = (short)f2bf(__fsub_rn(pp[2], q2));
            }
            *(u16x8*)&featl[sr * 104 + 64] = dv;
            *(u16x8*)&featl[sr * 104 + 72] = z8;
            *(u16x8*)&featl[sr * 104 + 80] = z8;
            *(u16x8*)&featl[sr * 104 + 88] = z8;
        }
    }
    __syncthreads();

    // ---- Layer 1 MFMA: M=128, N=64, K=96
    {
        f32x4 acc[2][4];
#pragma unroll
        for (int i = 0; i < 2; ++i)
#pragma unroll
            for (int nt = 0; nt < 4; ++nt) acc[i][nt] = (f32x4){0.f, 0.f, 0.f, 0.f};
#pragma unroll
        for (int ks = 0; ks < 3; ++ks) {
            bf16x8 afr[2];
#pragma unroll
            for (int i = 0; i < 2; ++i)
                afr[i] = *(const bf16x8*)&featl[((2 * wave + i) * 16 + l16) * 104 + ks * 32 + quad * 8];
#pragma unroll
            for (int nt = 0; nt < 4; ++nt) {
                bf16x8 bfr = *(const bf16x8*)(W1T + (nt * 16 + l16) * 96 + ks * 32 + quad * 8);
                acc[0][nt] = MFMA16(afr[0], bfr, acc[0][nt]);
                acc[1][nt] = MFMA16(afr[1], bfr, acc[1][nt]);
            }
        }
#pragma unroll
        for (int i = 0; i < 2; ++i)
#pragma unroll
            for (int nt = 0; nt < 4; ++nt) {
                int col = nt * 16 + l16;
                float bias = bc1[col];
#pragma unroll
                for (int reg = 0; reg < 4; ++reg) {
                    int row = (2 * wave + i) * 16 + quad * 4 + reg;
                    h1[row * 72 + col] = f2bf(lrelu01(acc[i][nt][reg] + bias));
                }
            }
    }
    __syncthreads();

    // ---- Layer 2 MFMA: M=128, N=128, K=64 (h2 aliases feat)
    {
        f32x4 acc[2][8];
#pragma unroll
        for (int i = 0; i < 2; ++i)
#pragma unroll
            for (int nt = 0; nt < 8; ++nt) acc[i][nt] = (f32x4){0.f, 0.f, 0.f, 0.f};
#pragma unroll
        for (int ks = 0; ks < 2; ++ks) {
            bf16x8 afr[2];
#pragma unroll
            for (int i = 0; i < 2; ++i)
                afr[i] = *(const bf16x8*)&h1[((2 * wave + i) * 16 + l16) * 72 + ks * 32 + quad * 8];
#pragma unroll
            for (int nt = 0; nt < 8; ++nt) {
                bf16x8 bfr = *(const bf16x8*)(W2T + (nt * 16 + l16) * 64 + ks * 32 + quad * 8);
                acc[0][nt] = MFMA16(afr[0], bfr, acc[0][nt]);
                acc[1][nt] = MFMA16(afr[1], bfr, acc[1][nt]);
            }
        }
        __syncthreads();   // all reads of feat/h1 done before h2 overwrite
#pragma unroll
        for (int i = 0; i < 2; ++i)
#pragma unroll
            for (int nt = 0; nt < 8; ++nt) {
                int col = nt * 16 + l16;
                float bias = bc2[col];
#pragma unroll
                for (int reg = 0; reg < 4; ++reg) {
                    int row = (2 * wave + i) * 16 + quad * 4 + reg;
                    h2[row * 136 + col] = f2bf(lrelu01(acc[i][nt][reg] + bias));
                }
            }
    }
    __syncthreads();

    // ---- Layer 3 MFMA: M=128, N=512, K=128; masked max (mred aliases h1 - safe, h1 dead)
    for (int c3 = 0; c3 < 4; ++c3) {
        f32x4 acc[2][8];
#pragma unroll
        for (int i = 0; i < 2; ++i)
#pragma unroll
            for (int nt = 0; nt < 8; ++nt) acc[i][nt] = (f32x4){0.f, 0.f, 0.f, 0.f};
#pragma unroll
        for (int ks = 0; ks < 4; ++ks) {
            bf16x8 afr[2];
#pragma unroll
            for (int i = 0; i < 2; ++i)
                afr[i] = *(const bf16x8*)&h2[((2 * wave + i) * 16 + l16) * 136 + ks * 32 + quad * 8];
#pragma unroll
            for (int nt = 0; nt < 8; ++nt) {
                bf16x8 bfr = *(const bf16x8*)(W3T + ((size_t)((c3 * 8 + nt) * 16 + l16)) * 128 + ks * 32 + quad * 8);
                acc[0][nt] = MFMA16(afr[0], bfr, acc[0][nt]);
                acc[1][nt] = MFMA16(afr[1], bfr, acc[1][nt]);
            }
        }
#pragma unroll
        for (int nt = 0; nt < 8; ++nt) {
            float vmax = -3.402823466e+38f;
#pragma unroll
            for (int i = 0; i < 2; ++i)
#pragma unroll
                for (int reg = 0; reg < 4; ++reg)
                    if (vbits & (1 << (i * 4 + reg))) vmax = fmaxf(vmax, acc[i][nt][reg]);
            vmax = fmaxf(vmax, __shfl_xor(vmax, 16));
            vmax = fmaxf(vmax, __shfl_xor(vmax, 32));
            if (lane < 16) mred[wave * 512 + (c3 * 8 + nt) * 16 + l16] = vmax;
        }
    }
    __syncthreads();
    // ---- epilogue: write encin row (bf16, K padded to 576): [agg | newpos | 0]
    unsigned short* erow = encin + (size_t)bs * 576;
    for (int c = t; c < 576; c += 256) {
        unsigned short v;
        if (c < 512) {
            float m4 = fmaxf(fmaxf(mred[c], mred[512 + c]), fmaxf(mred[1024 + c], mred[1536 + c]));
            v = f2bf(lrelu01(m4 + bc3[c]));
        } else if (c < 515) {
            v = f2bf(c == 512 ? q0 : (c == 513 ? q1 : q2));
        } else v = 0;
        erow[c] = v;
    }
}

// ---------------------------------------------------------------- generic bf16 MFMA GEMM: 128x128 tile
// A bf16 [M][Ka] (row clamp for partial M-tiles), BT bf16 [N][Ka], bias fp32.
// act: 0 none, 1 relu, 2 lrelu. Output: outh (bf16) if non-null else outf (fp32), stride Ncols.
__global__ void __launch_bounds__(256, 3) mfma_gemm(
    const unsigned short* __restrict__ A, const unsigned short* __restrict__ BT,
    const float* __restrict__ bias, float* __restrict__ outf, unsigned short* __restrict__ outh,
    int M, int Ka, int Ncols, int act) {
    __shared__ __align__(16) unsigned short As[128 * 72];
    int t = threadIdx.x;
    int wave = t >> 6, lane = t & 63, quad = lane >> 4, l16 = lane & 15;
    int row0 = blockIdx.x * 128, col0 = blockIdx.y * 128;
    f32x4 acc[2][8];
#pragma unroll
    for (int i = 0; i < 2; ++i)
#pragma unroll
        for (int nt = 0; nt < 8; ++nt) acc[i][nt] = (f32x4){0.f, 0.f, 0.f, 0.f};
    int nk = Ka >> 6;
    int sr = t >> 1, sh = t & 1;
    int grow = row0 + sr; if (grow > M - 1) grow = M - 1;
    const unsigned short* Arow = A + (size_t)grow * Ka + sh * 32;
    for (int ks = 0; ks < nk; ++ks) {
        u16x8 av[4];
#pragma unroll
        for (int j = 0; j < 4; ++j) av[j] = *(const u16x8*)(Arow + ks * 64 + j * 8);
        __syncthreads();
#pragma unroll
        for (int j = 0; j < 4; ++j) *(u16x8*)&As[sr * 72 + sh * 32 + j * 8] = av[j];
        __syncthreads();
#pragma unroll
        for (int ks2 = 0; ks2 < 2; ++ks2) {
            bf16x8 afr[2];
            afr[0] = *(const bf16x8*)&As[((2 * wave) * 16 + l16) * 72 + ks2 * 32 + quad * 8];
            afr[1] = *(const bf16x8*)&As[((2 * wave + 1) * 16 + l16) * 72 + ks2 * 32 + quad * 8];
#pragma unroll
            for (int nt = 0; nt < 8; ++nt) {
                bf16x8 bfr = *(const bf16x8*)(BT + (size_t)(col0 + nt * 16 + l16) * Ka + ks * 64 + ks2 * 32 + quad * 8);
                acc[0][nt] = MFMA16(afr[0], bfr, acc[0][nt]);
                acc[1][nt] = MFMA16(afr[1], bfr, acc[1][nt]);
            }
        }
    }
#pragma unroll
    for (int i = 0; i < 2; ++i)
#pragma unroll
        for (int nt = 0; nt < 8; ++nt) {
            int col = col0 + nt * 16 + l16;
            float bv = bias[col];
#pragma unroll
            for (int reg = 0; reg < 4; ++reg) {
                int row = row0 + (2 * wave + i) * 16 + quad * 4 + reg;
                if (row < M) {
                    float v = acc[i][nt][reg] + bv;
                    if (act == 1) v = fmaxf(v, 0.f);
                    else if (act == 2) v = lrelu01(v);
                    if (outh) outh[(size_t)row * Ncols + col] = f2bf(v);
                    else outf[(size_t)row * Ncols + col] = v;
                }
            }
        }
}

// ---------------------------------------------------------------- 8) vote aggregation
__global__ void votes_kernel(const float* __restrict__ e, float* __restrict__ z) {
    int o = blockIdx.x * 256 + threadIdx.x;          // 8192 exact
    int b = o >> 10, c = o & 1023;
    const float* eb = e + (size_t)b * SSAMP * 2048;
    float num = 0.f, den = 0.f;
    for (int s = 0; s < SSAMP; ++s) {
        float mean = eb[(size_t)s * 2048 + c];
        float lv = eb[(size_t)s * 2048 + 1024 + c];
        float sd = expf(0.5f * lv);
        num += mean / sd;
        den += 1.f / sd;
    }
    z[o] = num / den;
}

// ---------------------------------------------------------------- 9) u = z @ Wf[0:1024] + b (K-split x4, LDS z-transpose)
__global__ void __launch_bounds__(256) ukern(const float* __restrict__ z,
                                             const float* __restrict__ Wf11, const float* __restrict__ bf11,
                                             const float* __restrict__ Wf21, const float* __restrict__ bf21,
                                             float* __restrict__ u1, float* __restrict__ u2) {
    __shared__ float zt[1024 * 8];      // zt[ci*8+r]
    __shared__ float red[4][64][8];
    const float* W = blockIdx.y ? Wf21 : Wf11;
    const float* bias = blockIdx.y ? bf21 : bf11;
    float* u = blockIdx.y ? u2 : u1;
    int t = threadIdx.x;
#pragma unroll
    for (int i = 0; i < 32; ++i) {
        int o = t + i * 256;
        zt[(o & 1023) * 8 + (o >> 10)] = z[o];
    }
    __syncthreads();
    int c64 = t & 63, kc = t >> 6;
    int co = blockIdx.x * 64 + c64;
    float acc[8];
#pragma unroll
    for (int r = 0; r < 8; ++r) acc[r] = 0.f;
    for (int i = 0; i < 256; ++i) {
        int ci = kc * 256 + i;
        float w = W[(size_t)ci * 512 + co];
        const float4* zp = (const float4*)&zt[ci * 8];
        float4 z0 = zp[0], z1 = zp[1];
        acc[0] = fmaf(z0.x, w, acc[0]); acc[1] = fmaf(z0.y, w, acc[1]);
        acc[2] = fmaf(z0.z, w, acc[2]); acc[3] = fmaf(z0.w, w, acc[3]);
        acc[4] = fmaf(z1.x, w, acc[4]); acc[5] = fmaf(z1.y, w, acc[5]);
        acc[6] = fmaf(z1.z, w, acc[6]); acc[7] = fmaf(z1.w, w, acc[7]);
    }
#pragma unroll
    for (int r = 0; r < 8; ++r) red[kc][c64][r] = acc[r];
    __syncthreads();
    if (kc == 0) {
#pragma unroll
        for (int r = 0; r < 8; ++r) {
            float v = red[0][c64][r] + red[1][c64][r] + red[2][c64][r] + red[3][c64][r] + bias[co];
            u[r * 512 + co] = v;
        }
    }
}

// ---------------------------------------------------------------- 10) fold1 first layer -> bf16
__global__ void fold1_kernel(const float* __restrict__ u1, const float* __restrict__ Wf11,
                             unsigned short* __restrict__ f1) {
    int o = blockIdx.x * 256 + threadIdx.x;          // 8*2025*512 exact
    int co = o & 511;
    int rg = o >> 9;
    int b = rg / 2025;
    int g = rg - b * 2025;
    int i = g / 45, j = g - i * 45;
    float gx = (j == 44) ? 0.3f : (float)(-0.3 + j * (0.6 / 44.0));
    float gy = (i == 44) ? 0.3f : (float)(-0.3 + i * (0.6 / 44.0));
    float v = u1[(b << 9) + co];
    v = fmaf(gx, Wf11[1024 * 512 + co], v);
    v = fmaf(gy, Wf11[1025 * 512 + co], v);
    f1[o] = f2bf(fmaxf(v, 0.f));
}

// ---------------------------------------------------------------- 13) fold2 first layer -> bf16
__global__ void fold2_kernel(const float* __restrict__ u2, const float* __restrict__ Wf21,
                             const float* __restrict__ pts, unsigned short* __restrict__ f2) {
    int o = blockIdx.x * 256 + threadIdx.x;
    int co = o & 511;
    int rg = o >> 9;
    int b = rg / 2025;
    float p0 = pts[rg * 3 + 0], p1 = pts[rg * 3 + 1], p2 = pts[rg * 3 + 2];
    float v = u2[(b << 9) + co];
    v = fmaf(p0, Wf21[1024 * 512 + co], v);
    v = fmaf(p1, Wf21[1025 * 512 + co], v);
    v = fmaf(p2, Wf21[1026 * 512 + co], v);
    f2[o] = f2bf(fmaxf(v, 0.f));
}

// ---------------------------------------------------------------- final 512->3 projections (bf16 H)
__global__ void smallout_kernel(const unsigned short* __restrict__ H, const float* __restrict__ Wf,
                                const float* __restrict__ bf, float* __restrict__ out, int total) {
    int o = blockIdx.x * 256 + threadIdx.x;
    if (o >= total) return;
    int rg = o / 3, c = o - rg * 3;
    const unsigned int* h = (const unsigned int*)(H + (size_t)rg * 512);
    float a0 = 0.f, a1 = 0.f, a2 = 0.f, a3 = 0.f;
    for (int q = 0; q < 128; ++q) {
        unsigned int p0 = h[q * 2], p1 = h[q * 2 + 1];
        float e0 = __uint_as_float(p0 << 16);
        float e1 = __uint_as_float(p0 & 0xFFFF0000u);
        float e2 = __uint_as_float(p1 << 16);
        float e3 = __uint_as_float(p1 & 0xFFFF0000u);
        int k0 = q * 4;
        a0 = fmaf(e0, Wf[(k0 + 0) * 3 + c], a0);
        a1 = fmaf(e1, Wf[(k0 + 1) * 3 + c], a1);
        a2 = fmaf(e2, Wf[(k0 + 2) * 3 + c], a2);
        a3 = fmaf(e3, Wf[(k0 + 3) * 3 + c], a3);
    }
    out[o] = a0 + a1 + a2 + a3 + bf[c];
}

extern "C" void kernel_launch(void* const* d_in, const int* in_sizes, int n_in,
                              void* d_out, int out_size, void* d_ws, size_t ws_size,
                              hipStream_t stream) {
    const float* pos  = (const float*)d_in[0];
    const float* Wt   = (const float*)d_in[1];
    const float* bt   = (const float*)d_in[2];
    const float* Wc1  = (const float*)d_in[3];
    const float* bc1  = (const float*)d_in[4];
    const float* Wc2  = (const float*)d_in[5];
    const float* bc2  = (const float*)d_in[6];
    const float* Wc3  = (const float*)d_in[7];
    const float* bc3  = (const float*)d_in[8];
    const float* We1  = (const float*)d_in[9];
    const float* be1  = (const float*)d_in[10];
    const float* We2  = (const float*)d_in[11];
    const float* be2  = (const float*)d_in[12];
    const float* Wf11 = (const float*)d_in[13];
    const float* bf11 = (const float*)d_in[14];
    const float* Wf12 = (const float*)d_in[15];
    const float* bf12 = (const float*)d_in[16];
    const float* Wf13 = (const float*)d_in[17];
    const float* bf13 = (const float*)d_in[18];
    const float* Wf21 = (const float*)d_in[19];
    const float* bf21 = (const float*)d_in[20];
    const float* Wf22 = (const float*)d_in[21];
    const float* bf22 = (const float*)d_in[22];
    const float* Wf23 = (const float*)d_in[23];
    const float* bf23 = (const float*)d_in[24];
    float* out = (float*)d_out;

    float* wsf = (float*)d_ws;
    size_t off = 0;
    unsigned short* xbf   = (unsigned short*)(wsf + off); off += 1048576;  // [B*N][64] bf16
    unsigned short* encinh= (unsigned short*)(wsf + off); off += 589824;   // [2048][576] bf16
    unsigned short* e1h   = (unsigned short*)(wsf + off); off += 524288;   // [2048][512] bf16
    float* e    = wsf + off; off += 4194304;   // [2048][2048] fp32
    unsigned short* f1h   = (unsigned short*)(wsf + off); off += 4147200;  // [16200][512] bf16
    unsigned short* h12h  = (unsigned short*)(wsf + off); off += 4147200;  // [16200][512] bf16
    float* zb   = wsf + off; off += 8192;      // [8][1024]
    float* u1   = wsf + off; off += 4096;
    float* u2   = wsf + off; off += 4096;
    float* pts  = wsf + off; off += 48600;     // [16200][3]
    float* newp = wsf + off; off += 6144;      // [B,S,3]
    int*   fpsix = (int*)(wsf + off); off += 2048;
    int*   nix   = (int*)(wsf + off); off += 262144;
    unsigned short* W1T   = (unsigned short*)(wsf + off); off += 3072;     // 64x96
    unsigned short* W2T   = (unsigned short*)(wsf + off); off += 4096;     // 128x64
    unsigned short* W3T   = (unsigned short*)(wsf + off); off += 32768;    // 512x128
    unsigned short* We1T  = (unsigned short*)(wsf + off); off += 147456;   // 512x576
    unsigned short* We2T  = (unsigned short*)(wsf + off); off += 524288;   // 2048x512
    unsigned short* Wf12T = (unsigned short*)(wsf + off); off += 131072;   // 512x512
    unsigned short* Wf22T = (unsigned short*)(wsf + off); off += 131072;   // 512x512

    preconv_kernel<<<7608, 256, 0, stream>>>(Wc1, Wc2, Wc3, We1, We2, Wf12, Wf22,
                                             W1T, W2T, W3T, We1T, We2T, Wf12T, Wf22T);
    xform_kernel<<<8192, 256, 0, stream>>>(pos, Wt, bt, xbf);
    fps_kernel<<<BATCH, 512, 0, stream>>>(pos, fpsix, newp);
    ballq_kernel<<<512, 256, 0, stream>>>(pos, newp, nix);
    pointconv_kernel<<<2048, 256, 0, stream>>>(xbf, pos, newp, nix, W1T, W2T, W3T,
                                               bc1, bc2, bc3, encinh);
    mfma_gemm<<<dim3(16, 4), 256, 0, stream>>>(encinh, We1T, be1, nullptr, e1h, 2048, 576, 512, 2);
    mfma_gemm<<<dim3(16, 16), 256, 0, stream>>>(e1h, We2T, be2, e, nullptr, 2048, 512, 2048, 0);
    votes_kernel<<<32, 256, 0, stream>>>(e, zb);
    ukern<<<dim3(8, 2), 256, 0, stream>>>(zb, Wf11, bf11, Wf21, bf21, u1, u2);
    fold1_kernel<<<32400, 256, 0, stream>>>(u1, Wf11, f1h);
    mfma_gemm<<<dim3(127, 4), 256, 0, stream>>>(f1h, Wf12T, bf12, nullptr, h12h, 16200, 512, 512, 1);
    smallout_kernel<<<190, 256, 0, stream>>>(h12h, Wf13, bf13, pts, 48600);
    fold2_kernel<<<32400, 256, 0, stream>>>(u2, Wf21, pts, f1h);
    mfma_gemm<<<dim3(127, 4), 256, 0, stream>>>(f1h, Wf22T, bf22, nullptr, h12h, 16200, 512, 512, 1);
    smallout_kernel<<<190, 256, 0, stream>>>(h12h, Wf23, bf23, out, 48600);
}